// Round 6
// baseline (441.204 us; speedup 1.0000x reference)
//
#include <hip/hip_runtime.h>
#include <math.h>

#define N_ANCH 120000
#define N_CLS  80
#define TOPK   4096
#define MAXDET 100
#define CONF   0.25f
#define IOUT   0.4f
#define DBLK   128   // anchors per decode block

// ---------- helpers ----------
__device__ __forceinline__ unsigned f2ord(float f) {
    unsigned u = __float_as_uint(f);
    return (u & 0x80000000u) ? ~u : (u | 0x80000000u);
}
__device__ __forceinline__ float ord2f(unsigned o) {
    unsigned u = (o & 0x80000000u) ? (o & 0x7FFFFFFFu) : ~o;
    return __uint_as_float(u);
}
#define ORD_NEGINF 0x007FFFFFu   // f2ord(-INFINITY)

// ---------- 0: zero hist + meta ----------
__global__ __launch_bounds__(1024) void k_zero(unsigned* hist, unsigned* meta) {
    int i = blockIdx.x * 1024 + threadIdx.x;
    if (i < 65536) hist[i] = 0u;
    if (i < 64) meta[i] = 0u;
}

// ---------- 1: decode anchors (LDS-staged, coalesced) + histogram round 1 ----------
__global__ __launch_bounds__(DBLK) void k_decode(const float* __restrict__ pred,
                                                 unsigned* __restrict__ ord,
                                                 int* __restrict__ lab,
                                                 float4* __restrict__ box,
                                                 unsigned* __restrict__ hist) {
    __shared__ float s[DBLK * 85];   // 43520 B
    int blk = blockIdx.x;
    long basef = (long)blk * (DBLK * 85);
    long remf = (long)N_ANCH * 85 - basef;
    int nf = (int)(remf < (long)(DBLK * 85) ? remf : (long)(DBLK * 85));
    int tot4 = nf >> 2;  // all block float-counts are multiples of 4
    const float4* g4 = (const float4*)(pred + basef);
    float4* s4 = (float4*)s;
    for (int i = threadIdx.x; i < tot4; i += DBLK) s4[i] = g4[i];
    __syncthreads();
    int a = blk * DBLK + threadIdx.x;
    if (a >= N_ANCH) return;
    const float* p = s + threadIdx.x * 85;  // bank = (21*lane + c) % 32 -> 2-way, free
    float x = p[0], y = p[1], w = p[2], h = p[3], obj = p[4];
    float best = p[5];
    int bl = 0;
    for (int c = 1; c < N_CLS; ++c) {
        float v = p[5 + c];
        if (v > best) { best = v; bl = c; }   // first-max (argmax) semantics
    }
    float sc = obj * best;
    float hw = w * 0.5f, hh = h * 0.5f;
    float4 b;
    b.x = x - hw; b.y = y - hh; b.z = x + hw; b.w = y + hh;
    bool valid = sc > CONF;
    float m = valid ? sc : -INFINITY;
    unsigned o = f2ord(m);
    ord[a] = o;
    lab[a] = bl;
    box[a] = b;
    unsigned long long balInv = __ballot(!valid);
    if (valid) {
        atomicAdd(&hist[o >> 16], 1u);   // ~300 distinct exponent bins: distributed, cheap
    } else {
        int lane = threadIdx.x & 63;
        if (lane == __ffsll(balInv) - 1)
            atomicAdd(&hist[ORD_NEGINF >> 16], (unsigned)__popcll(balInv));
    }
}

// ---------- 2/4: histogram select (suffix scan over 65536 bins) ----------
__global__ __launch_bounds__(1024) void k_select(unsigned* hist, unsigned* meta, int mode) {
    __shared__ unsigned part[1024];
    int t = threadIdx.x;
    unsigned target = (mode == 0) ? (unsigned)TOPK : meta[2];
    int base = t * 64;
    unsigned local = 0;
    for (int i = 0; i < 64; ++i) local += hist[base + i];
    part[t] = local;
    __syncthreads();
    for (int off = 1; off < 1024; off <<= 1) {
        unsigned v = (t + off < 1024) ? part[t + off] : 0u;
        __syncthreads();
        part[t] += v;
        __syncthreads();
    }
    unsigned incl = part[t];
    unsigned after = (t + 1 < 1024) ? part[t + 1] : 0u;
    if (after < target && incl >= target) {
        unsigned c64[64];
#pragma unroll
        for (int i = 0; i < 64; ++i) c64[i] = hist[base + i];  // independent, pipelined
        unsigned run = after;
        for (int i = 63; i >= 0; --i) {
            unsigned c = c64[i];
            if (run + c >= target) {
                if (mode == 0) {
                    meta[0] = (unsigned)(base + i);
                    meta[1] = run;
                    meta[2] = (unsigned)TOPK - run;
                } else {
                    meta[3] = (meta[0] << 16) | (unsigned)(base + i);
                    meta[4] = meta[1] + run;
                    meta[5] = meta[2] - run;
                }
                break;
            }
            run += c;
        }
    }
    if (mode == 0) {
        for (int i = 0; i < 64; ++i) hist[base + i] = 0u;
    }
}

// ---------- 3: histogram round 2 (aggregate the constant -inf pattern defensively) ----------
__global__ __launch_bounds__(256) void k_hist2(const unsigned* __restrict__ ord,
                                               const unsigned* __restrict__ meta,
                                               unsigned* __restrict__ hist) {
    int a = blockIdx.x * 256 + threadIdx.x;
    if (a >= N_ANCH) return;
    unsigned o = ord[a];
    bool inBin = ((o >> 16) == meta[0]);
    bool isInv = inBin && (o == ORD_NEGINF);
    unsigned long long balInv = __ballot(isInv);
    if (inBin) {
        if (isInv) {
            int lane = threadIdx.x & 63;
            if (lane == __ffsll(balInv) - 1)
                atomicAdd(&hist[ORD_NEGINF & 0xFFFFu], (unsigned)__popcll(balInv));
        } else {
            atomicAdd(&hist[o & 0xFFFFu], 1u);
        }
    }
}

// ---------- 5: compact (warp-aggregated counter atomics; order within sets irrelevant) ----------
__global__ __launch_bounds__(256) void k_compact(const unsigned* __restrict__ ord,
                                                 unsigned* meta,
                                                 unsigned long long* __restrict__ keys,
                                                 unsigned* __restrict__ eq) {
    int a = blockIdx.x * 256 + threadIdx.x;
    if (a >= N_ANCH) return;
    unsigned o = ord[a];
    unsigned T = meta[3];
    int lane = threadIdx.x & 63;
    bool isGt = (o > T);
    bool isEq = (o == T);
    unsigned long long balGt = __ballot(isGt);
    unsigned long long balEq = __ballot(isEq);
    if (isGt) {
        int leader = __ffsll(balGt) - 1;
        unsigned base = 0;
        if (lane == leader) base = atomicAdd(&meta[6], (unsigned)__popcll(balGt));
        base = (unsigned)__shfl((int)base, leader);
        unsigned p = base + (unsigned)__popcll(balGt & ((1ull << lane) - 1ull));
        keys[p] = ((unsigned long long)o << 32) | (unsigned)(~(unsigned)a);
    } else if (isEq) {
        int leader = __ffsll(balEq) - 1;
        unsigned base = 0;
        if (lane == leader) base = atomicAdd(&meta[7], (unsigned)__popcll(balEq));
        base = (unsigned)__shfl((int)base, leader);
        unsigned p = base + (unsigned)__popcll(balEq & ((1ull << lane) - 1ull));
        if (p < TOPK) eq[p] = (unsigned)a;
    }
}

// ---------- 6: tie handling. Membership = remEq smallest tie indices. ----------
__global__ __launch_bounds__(1024) void k_eqsort(const unsigned* __restrict__ eq,
                                                 unsigned* meta,
                                                 unsigned long long* keys) {
    __shared__ unsigned s[TOPK];
    int t = threadIdx.x;
    unsigned n = meta[7]; if (n > TOPK) n = TOPK;
    unsigned remEq = meta[5];
    unsigned baseA = meta[4];
    unsigned T = meta[3];
    if (remEq == 0) return;
    if (n > remEq) {
        unsigned m = 1; while (m < n) m <<= 1;
        for (unsigned i = t; i < m; i += 1024) s[i] = (i < n) ? eq[i] : 0xFFFFFFFFu;
        __syncthreads();
        for (unsigned k = 2; k <= m; k <<= 1)
            for (unsigned j = k >> 1; j > 0; j >>= 1) {
                for (unsigned idx = t; idx < m; idx += 1024) {
                    unsigned ixj = idx ^ j;
                    if (ixj > idx) {
                        unsigned a = s[idx], b = s[ixj];
                        bool asc = ((idx & k) == 0);
                        bool sw = asc ? (a > b) : (a < b);
                        if (sw) { s[idx] = b; s[ixj] = a; }
                    }
                }
                __syncthreads();
            }
        for (unsigned r = t; r < remEq; r += 1024)
            keys[baseA + r] = ((unsigned long long)T << 32) | (unsigned)(~s[r]);
    } else {
        for (unsigned r = t; r < remEq; r += 1024)
            keys[baseA + r] = ((unsigned long long)T << 32) | (unsigned)(~eq[r]);
    }
}

// ---------- 7: bitonic sort 4096 keys descending ----------
__global__ __launch_bounds__(1024) void k_sort(unsigned long long* keys) {
    __shared__ unsigned long long s[TOPK];
    int t = threadIdx.x;
    for (int i = t; i < TOPK; i += 1024) s[i] = keys[i];
    __syncthreads();
    for (int k = 2; k <= TOPK; k <<= 1)
        for (int j = k >> 1; j > 0; j >>= 1) {
            for (int idx = t; idx < TOPK; idx += 1024) {
                int ixj = idx ^ j;
                if (ixj > idx) {
                    unsigned long long a = s[idx], b = s[ixj];
                    bool desc = ((idx & k) == 0);
                    bool sw = desc ? (a < b) : (a > b);
                    if (sw) { s[idx] = b; s[ixj] = a; }
                }
            }
            __syncthreads();
        }
    for (int i = t; i < TOPK; i += 1024) keys[i] = s[i];
}

// ---------- 8: gather + max_coord ----------
__global__ __launch_bounds__(256) void k_gather(const unsigned long long* __restrict__ keys,
                                                const int* __restrict__ lab,
                                                const float4* __restrict__ box,
                                                int* __restrict__ cIdx,
                                                float* __restrict__ cScore,
                                                int* __restrict__ cLab,
                                                float4* __restrict__ cBox,
                                                unsigned* meta) {
    int k = blockIdx.x * 256 + threadIdx.x;
    unsigned long long key = keys[k];
    unsigned o = (unsigned)(key >> 32);
    unsigned a = ~(unsigned)(key & 0xFFFFFFFFu);
    float sc = ord2f(o);
    cIdx[k] = (int)a;
    cScore[k] = sc;
    cLab[k] = lab[a];
    float4 b = box[a];
    cBox[k] = b;
    if (sc > CONF) {
        if (b.x > 0.f) atomicMax(&meta[8], __float_as_uint(b.x));
        if (b.y > 0.f) atomicMax(&meta[8], __float_as_uint(b.y));
        if (b.z > 0.f) atomicMax(&meta[8], __float_as_uint(b.z));
        if (b.w > 0.f) atomicMax(&meta[8], __float_as_uint(b.w));
    }
}

// ---------- 9: offset boxes + areas ----------
__global__ __launch_bounds__(256) void k_offbox(const int* __restrict__ cLab,
                                                const float4* __restrict__ cBox,
                                                const unsigned* __restrict__ meta,
                                                float4* __restrict__ oBox,
                                                float* __restrict__ oArea) {
    int k = blockIdx.x * 256 + threadIdx.x;
    float mc = __uint_as_float(meta[8]) + 1.0f;
    float off = (float)cLab[k] * mc;
    float4 b = cBox[k];
    float4 ob;
    ob.x = b.x + off; ob.y = b.y + off; ob.z = b.z + off; ob.w = b.w + off;
    oBox[k] = ob;
    oArea[k] = fmaxf(ob.z - ob.x, 0.f) * fmaxf(ob.w - ob.y, 0.f);
}

// ---------- 10: suppression bitmask ----------
__global__ __launch_bounds__(256) void k_mask(const float4* __restrict__ oBox,
                                              const float* __restrict__ oArea,
                                              unsigned long long* __restrict__ M) {
    int w = threadIdx.x;
    int i = blockIdx.x * 4 + threadIdx.y;
    float4 bi = oBox[i];
    float ai = oArea[i];
    unsigned long long bits = 0ull;
    int j0 = w << 6;
    for (int b = 0; b < 64; ++b) {
        int j = j0 + b;
        float4 bj = oBox[j];
        float aj = oArea[j];
        float ix1 = fmaxf(bi.x, bj.x), iy1 = fmaxf(bi.y, bj.y);
        float ix2 = fminf(bi.z, bj.z), iy2 = fminf(bi.w, bj.w);
        float inter = fmaxf(ix2 - ix1, 0.f) * fmaxf(iy2 - iy1, 0.f);
        float uni = ai + aj - inter;
        float iou = inter / fmaxf(uni, 1e-9f);
        if ((j > i) & (iou > IOUT)) bits |= (1ull << b);
    }
    M[(long)i * 64 + w] = bits;
}

// ---------- 11: greedy NMS, single wave, 64x64 tiled, register double-buffered ----------
// __launch_bounds__(64, 1): 1 wave/EU -> allocator may use ~450+ VGPRs, so
// RA[64]+RB[64] (256 VGPR) stay in registers (round-5 spilled at cap 192).
// Pass A: readlane -> wave-UNIFORM values; the 64-step greedy chain runs on the
// SALU (s_lshr_b64/s_cselect_b64/s_or_b64, ~1-2cy dep) in parallel with the
// VALU readlane stream. Pass B: uniform kt masks = SGPR operands to v_and.
__global__ __launch_bounds__(64, 1) void k_nms(const unsigned long long* __restrict__ M,
                                               const float* __restrict__ cScore,
                                               unsigned long long* __restrict__ keepW) {
    int lane = threadIdx.x;
    unsigned long long S = 0ull;
    // invalid-score bits: word b = ballot of lanes reading cScore[b*64+lane] (coalesced)
#pragma unroll 8
    for (int b = 0; b < 64; ++b) {
        float sc = cScore[(b << 6) + lane];
        unsigned long long bal = __ballot(!(sc > CONF));
        if (lane == b) S = bal;
    }
    const unsigned long long* Ml = M + lane;
    unsigned long long RA[64], RB[64];
#pragma unroll
    for (int b = 0; b < 64; ++b) RA[b] = Ml[(long)b * 64];

#define NMS_TILE(R, t)                                                                              \
    {                                                                                               \
        unsigned long long s_tile =                                                                 \
            ((unsigned long long)(unsigned)__builtin_amdgcn_readlane((int)(unsigned)(S >> 32), (t)) \
             << 32) |                                                                               \
            (unsigned)__builtin_amdgcn_readlane((int)(unsigned)S, (t));                             \
        _Pragma("unroll")                                                                           \
        for (int b = 0; b < 64; ++b) {                                                              \
            unsigned rl = (unsigned)__builtin_amdgcn_readlane((int)(unsigned)R[b], (t));            \
            unsigned rh = (unsigned)__builtin_amdgcn_readlane((int)(unsigned)(R[b] >> 32), (t));    \
            unsigned long long row = ((unsigned long long)rh << 32) | rl;                           \
            s_tile |= (((s_tile >> b) & 1ull) == 0ull) ? row : 0ull;  /* uniform: SALU cselect */   \
        }                                                                                           \
        unsigned long long kt = ~s_tile;  /* uniform keep mask for this tile's rows */              \
        unsigned long long a0 = 0, a1 = 0, a2 = 0, a3 = 0, a4 = 0, a5 = 0, a6 = 0, a7 = 0;          \
        _Pragma("unroll")                                                                           \
        for (int b = 0; b < 64; b += 8) {                                                           \
            a0 |= R[b + 0] & (0ull - ((kt >> (b + 0)) & 1ull));                                     \
            a1 |= R[b + 1] & (0ull - ((kt >> (b + 1)) & 1ull));                                     \
            a2 |= R[b + 2] & (0ull - ((kt >> (b + 2)) & 1ull));                                     \
            a3 |= R[b + 3] & (0ull - ((kt >> (b + 3)) & 1ull));                                     \
            a4 |= R[b + 4] & (0ull - ((kt >> (b + 4)) & 1ull));                                     \
            a5 |= R[b + 5] & (0ull - ((kt >> (b + 5)) & 1ull));                                     \
            a6 |= R[b + 6] & (0ull - ((kt >> (b + 6)) & 1ull));                                     \
            a7 |= R[b + 7] & (0ull - ((kt >> (b + 7)) & 1ull));                                     \
        }                                                                                           \
        S |= ((a0 | a1) | (a2 | a3)) | ((a4 | a5) | (a6 | a7));                                     \
    }

    for (int t = 0; t < 64; t += 2) {
        // prefetch tile t+1 (always exists: t max = 62)
#pragma unroll
        for (int b = 0; b < 64; ++b) RB[b] = Ml[(long)((t + 1) * 64 + b) * 64];
        NMS_TILE(RA, t);
        if (t + 2 < 64) {
#pragma unroll
            for (int b = 0; b < 64; ++b) RA[b] = Ml[(long)((t + 2) * 64 + b) * 64];
        }
        NMS_TILE(RB, t + 1);
    }
#undef NMS_TILE
    keepW[lane] = ~S;
}

// ---------- 12: finalize ----------
__global__ __launch_bounds__(256) void k_final(const unsigned long long* __restrict__ keepW,
                                               const float* __restrict__ cScore,
                                               const float4* __restrict__ cBox,
                                               const int* __restrict__ cIdx,
                                               const float* __restrict__ pred,
                                               const int* __restrict__ img,
                                               const int* __restrict__ inp,
                                               float* __restrict__ out,
                                               int out_size) {
    __shared__ int sel[MAXDET];
    __shared__ int nsel;
    int t = threadIdx.x;
    for (int i = t; i < out_size; i += 256) out[i] = 0.f;
    if (t == 0) nsel = 0;
    __syncthreads();
    if (t < 64) {
        unsigned long long kw = keepW[t];
        int cnt = __popcll(kw);
        int incl = cnt;
        for (int off = 1; off < 64; off <<= 1) {
            int v = __shfl_up(incl, off);
            if (t >= off) incl += v;
        }
        int rk = incl - cnt;
        if (t == 63) nsel = (incl < MAXDET) ? incl : MAXDET;
        unsigned long long m = kw;
        while (m) {
            int b = __ffsll((unsigned long long)m) - 1;
            m &= m - 1;
            if (rk < MAXDET) sel[rk] = (t << 6) + b;
            ++rk;
        }
    }
    __syncthreads();
    int nk = nsel;
    int ih_i = img[0], iw_i = img[1];
    int nh_i = inp[0], nw_i = inp[1];
    if (iw_i == 0) iw_i = img[2];
    if (nw_i == 0) nw_i = inp[2];
    float ih = (float)ih_i, iw = (float)iw_i;
    float nh = (float)nh_i, nw = (float)nw_i;
    float gain = fminf(nh / ih, nw / iw);
    float pad0 = (nh - ih * gain) * 0.5f;
    float pad1 = (nw - iw * gain) * 0.5f;
    for (int o = t; o < nk; o += 256) {
        int k = sel[o];
        float4 b = cBox[k];
        float x1 = fminf(fmaxf((b.x - pad1) / gain, 0.f), iw);
        float y1 = fminf(fmaxf((b.y - pad0) / gain, 0.f), ih);
        float x2 = fminf(fmaxf((b.z - pad1) / gain, 0.f), iw);
        float y2 = fminf(fmaxf((b.w - pad0) / gain, 0.f), ih);
        out[o * 4 + 0] = (x1 + x2) * 0.5f / iw;
        out[o * 4 + 1] = (y1 + y2) * 0.5f / ih;
        out[o * 4 + 2] = (x2 - x1) / iw;
        out[o * 4 + 3] = (y2 - y1) / ih;
        out[4 * MAXDET + o] = cScore[k];
    }
    for (int p = t; p < nk * N_CLS; p += 256) {
        int o = p / N_CLS, c = p - o * N_CLS;
        int a = cIdx[sel[o]];
        out[5 * MAXDET + p] = pred[(long)a * 85 + 5 + c];
    }
}

extern "C" void kernel_launch(void* const* d_in, const int* in_sizes, int n_in,
                              void* d_out, int out_size, void* d_ws, size_t ws_size,
                              hipStream_t stream) {
    const float* pred = (const float*)d_in[0];
    const int* img = (const int*)d_in[1];
    const int* inp = (const int*)d_in[2];
    float* out = (float*)d_out;
    unsigned char* W = (unsigned char*)d_ws;

    unsigned* hist                = (unsigned*)(W + 0);                // 262144 B
    unsigned* meta                = (unsigned*)(W + 262144);           // 256 B
    unsigned* ord                 = (unsigned*)(W + 262400);           // 480000 B
    int* lab                      = (int*)(W + 742400);                // 480000 B
    float4* box                   = (float4*)(W + 1222400);            // 1920000 B
    unsigned long long* keys      = (unsigned long long*)(W + 3142400);// 32768 B
    unsigned* eq                  = (unsigned*)(W + 3175168);          // 16384 B
    int* cIdx                     = (int*)(W + 3191552);               // 16384 B
    float* cScore                 = (float*)(W + 3207936);             // 16384 B
    int* cLab                     = (int*)(W + 3224320);               // 16384 B
    float4* cBox                  = (float4*)(W + 3240704);            // 65536 B
    float4* oBox                  = (float4*)(W + 3306240);            // 65536 B
    float* oArea                  = (float*)(W + 3371776);             // 16384 B
    unsigned long long* M         = (unsigned long long*)(W + 3388160);// 2097152 B
    unsigned long long* keepW     = (unsigned long long*)(W + 5485312);// 512 B

    int nb = (N_ANCH + 255) / 256;
    int ndb = (N_ANCH + DBLK - 1) / DBLK;
    k_zero<<<64, 1024, 0, stream>>>(hist, meta);
    k_decode<<<ndb, DBLK, 0, stream>>>(pred, ord, lab, box, hist);
    k_select<<<1, 1024, 0, stream>>>(hist, meta, 0);
    k_hist2<<<nb, 256, 0, stream>>>(ord, meta, hist);
    k_select<<<1, 1024, 0, stream>>>(hist, meta, 1);
    k_compact<<<nb, 256, 0, stream>>>(ord, meta, keys, eq);
    k_eqsort<<<1, 1024, 0, stream>>>(eq, meta, keys);
    k_sort<<<1, 1024, 0, stream>>>(keys);
    k_gather<<<16, 256, 0, stream>>>(keys, lab, box, cIdx, cScore, cLab, cBox, meta);
    k_offbox<<<16, 256, 0, stream>>>(cLab, cBox, meta, oBox, oArea);
    k_mask<<<1024, dim3(64, 4), 0, stream>>>(oBox, oArea, M);
    k_nms<<<1, 64, 0, stream>>>(M, cScore, keepW);
    k_final<<<1, 256, 0, stream>>>(keepW, cScore, cBox, cIdx, pred, img, inp, out, out_size);
}

// Round 7
// 426.073 us; speedup vs baseline: 1.0355x; 1.0355x over previous
//
#include <hip/hip_runtime.h>
#include <math.h>

#define N_ANCH 120000
#define N_CLS  80
#define TOPK   4096
#define MAXDET 100
#define CONF   0.25f
#define IOUT   0.4f
#define DBLK   128   // anchors per decode block

// ---------- helpers ----------
__device__ __forceinline__ unsigned f2ord(float f) {
    unsigned u = __float_as_uint(f);
    return (u & 0x80000000u) ? ~u : (u | 0x80000000u);
}
__device__ __forceinline__ float ord2f(unsigned o) {
    unsigned u = (o & 0x80000000u) ? (o & 0x7FFFFFFFu) : ~o;
    return __uint_as_float(u);
}
#define ORD_NEGINF 0x007FFFFFu   // f2ord(-INFINITY)

// ---------- 0: zero hist + meta ----------
__global__ __launch_bounds__(1024) void k_zero(unsigned* hist, unsigned* meta) {
    int i = blockIdx.x * 1024 + threadIdx.x;
    if (i < 65536) hist[i] = 0u;
    if (i < 64) meta[i] = 0u;
}

// ---------- 1: decode anchors (LDS-staged, coalesced) + histogram round 1 ----------
__global__ __launch_bounds__(DBLK) void k_decode(const float* __restrict__ pred,
                                                 unsigned* __restrict__ ord,
                                                 int* __restrict__ lab,
                                                 float4* __restrict__ box,
                                                 unsigned* __restrict__ hist) {
    __shared__ float s[DBLK * 85];   // 43520 B
    int blk = blockIdx.x;
    long basef = (long)blk * (DBLK * 85);
    long remf = (long)N_ANCH * 85 - basef;
    int nf = (int)(remf < (long)(DBLK * 85) ? remf : (long)(DBLK * 85));
    int tot4 = nf >> 2;  // all block float-counts are multiples of 4
    const float4* g4 = (const float4*)(pred + basef);
    float4* s4 = (float4*)s;
    for (int i = threadIdx.x; i < tot4; i += DBLK) s4[i] = g4[i];
    __syncthreads();
    int a = blk * DBLK + threadIdx.x;
    if (a >= N_ANCH) return;
    const float* p = s + threadIdx.x * 85;  // bank = (21*lane + c) % 32 -> 2-way, free
    float x = p[0], y = p[1], w = p[2], h = p[3], obj = p[4];
    float best = p[5];
    int bl = 0;
    for (int c = 1; c < N_CLS; ++c) {
        float v = p[5 + c];
        if (v > best) { best = v; bl = c; }   // first-max (argmax) semantics
    }
    float sc = obj * best;
    float hw = w * 0.5f, hh = h * 0.5f;
    float4 b;
    b.x = x - hw; b.y = y - hh; b.z = x + hw; b.w = y + hh;
    bool valid = sc > CONF;
    float m = valid ? sc : -INFINITY;
    unsigned o = f2ord(m);
    ord[a] = o;
    lab[a] = bl;
    box[a] = b;
    unsigned long long balInv = __ballot(!valid);
    if (valid) {
        atomicAdd(&hist[o >> 16], 1u);   // ~300 distinct exponent bins: distributed, cheap
    } else {
        int lane = threadIdx.x & 63;
        if (lane == __ffsll(balInv) - 1)
            atomicAdd(&hist[ORD_NEGINF >> 16], (unsigned)__popcll(balInv));
    }
}

// ---------- 2/4: histogram select (suffix scan over 65536 bins) ----------
__global__ __launch_bounds__(1024) void k_select(unsigned* hist, unsigned* meta, int mode) {
    __shared__ unsigned part[1024];
    int t = threadIdx.x;
    unsigned target = (mode == 0) ? (unsigned)TOPK : meta[2];
    int base = t * 64;
    unsigned local = 0;
    for (int i = 0; i < 64; ++i) local += hist[base + i];
    part[t] = local;
    __syncthreads();
    for (int off = 1; off < 1024; off <<= 1) {
        unsigned v = (t + off < 1024) ? part[t + off] : 0u;
        __syncthreads();
        part[t] += v;
        __syncthreads();
    }
    unsigned incl = part[t];
    unsigned after = (t + 1 < 1024) ? part[t + 1] : 0u;
    if (after < target && incl >= target) {
        unsigned c64[64];
#pragma unroll
        for (int i = 0; i < 64; ++i) c64[i] = hist[base + i];  // independent, pipelined
        unsigned run = after;
        for (int i = 63; i >= 0; --i) {
            unsigned c = c64[i];
            if (run + c >= target) {
                if (mode == 0) {
                    meta[0] = (unsigned)(base + i);
                    meta[1] = run;
                    meta[2] = (unsigned)TOPK - run;
                } else {
                    meta[3] = (meta[0] << 16) | (unsigned)(base + i);
                    meta[4] = meta[1] + run;
                    meta[5] = meta[2] - run;
                }
                break;
            }
            run += c;
        }
    }
    if (mode == 0) {
        for (int i = 0; i < 64; ++i) hist[base + i] = 0u;
    }
}

// ---------- 3: histogram round 2 (aggregate the constant -inf pattern defensively) ----------
__global__ __launch_bounds__(256) void k_hist2(const unsigned* __restrict__ ord,
                                               const unsigned* __restrict__ meta,
                                               unsigned* __restrict__ hist) {
    int a = blockIdx.x * 256 + threadIdx.x;
    if (a >= N_ANCH) return;
    unsigned o = ord[a];
    bool inBin = ((o >> 16) == meta[0]);
    bool isInv = inBin && (o == ORD_NEGINF);
    unsigned long long balInv = __ballot(isInv);
    if (inBin) {
        if (isInv) {
            int lane = threadIdx.x & 63;
            if (lane == __ffsll(balInv) - 1)
                atomicAdd(&hist[ORD_NEGINF & 0xFFFFu], (unsigned)__popcll(balInv));
        } else {
            atomicAdd(&hist[o & 0xFFFFu], 1u);
        }
    }
}

// ---------- 5: compact (warp-aggregated counter atomics; order within sets irrelevant) ----------
__global__ __launch_bounds__(256) void k_compact(const unsigned* __restrict__ ord,
                                                 unsigned* meta,
                                                 unsigned long long* __restrict__ keys,
                                                 unsigned* __restrict__ eq) {
    int a = blockIdx.x * 256 + threadIdx.x;
    if (a >= N_ANCH) return;
    unsigned o = ord[a];
    unsigned T = meta[3];
    int lane = threadIdx.x & 63;
    bool isGt = (o > T);
    bool isEq = (o == T);
    unsigned long long balGt = __ballot(isGt);
    unsigned long long balEq = __ballot(isEq);
    if (isGt) {
        int leader = __ffsll(balGt) - 1;
        unsigned base = 0;
        if (lane == leader) base = atomicAdd(&meta[6], (unsigned)__popcll(balGt));
        base = (unsigned)__shfl((int)base, leader);
        unsigned p = base + (unsigned)__popcll(balGt & ((1ull << lane) - 1ull));
        keys[p] = ((unsigned long long)o << 32) | (unsigned)(~(unsigned)a);
    } else if (isEq) {
        int leader = __ffsll(balEq) - 1;
        unsigned base = 0;
        if (lane == leader) base = atomicAdd(&meta[7], (unsigned)__popcll(balEq));
        base = (unsigned)__shfl((int)base, leader);
        unsigned p = base + (unsigned)__popcll(balEq & ((1ull << lane) - 1ull));
        if (p < TOPK) eq[p] = (unsigned)a;
    }
}

// ---------- 6: tie handling. Membership = remEq smallest tie indices. ----------
__global__ __launch_bounds__(1024) void k_eqsort(const unsigned* __restrict__ eq,
                                                 unsigned* meta,
                                                 unsigned long long* keys) {
    __shared__ unsigned s[TOPK];
    int t = threadIdx.x;
    unsigned n = meta[7]; if (n > TOPK) n = TOPK;
    unsigned remEq = meta[5];
    unsigned baseA = meta[4];
    unsigned T = meta[3];
    if (remEq == 0) return;
    if (n > remEq) {
        unsigned m = 1; while (m < n) m <<= 1;
        for (unsigned i = t; i < m; i += 1024) s[i] = (i < n) ? eq[i] : 0xFFFFFFFFu;
        __syncthreads();
        for (unsigned k = 2; k <= m; k <<= 1)
            for (unsigned j = k >> 1; j > 0; j >>= 1) {
                for (unsigned idx = t; idx < m; idx += 1024) {
                    unsigned ixj = idx ^ j;
                    if (ixj > idx) {
                        unsigned a = s[idx], b = s[ixj];
                        bool asc = ((idx & k) == 0);
                        bool sw = asc ? (a > b) : (a < b);
                        if (sw) { s[idx] = b; s[ixj] = a; }
                    }
                }
                __syncthreads();
            }
        for (unsigned r = t; r < remEq; r += 1024)
            keys[baseA + r] = ((unsigned long long)T << 32) | (unsigned)(~s[r]);
    } else {
        for (unsigned r = t; r < remEq; r += 1024)
            keys[baseA + r] = ((unsigned long long)T << 32) | (unsigned)(~eq[r]);
    }
}

// ---------- 7: bitonic sort 4096 keys descending ----------
__global__ __launch_bounds__(1024) void k_sort(unsigned long long* keys) {
    __shared__ unsigned long long s[TOPK];
    int t = threadIdx.x;
    for (int i = t; i < TOPK; i += 1024) s[i] = keys[i];
    __syncthreads();
    for (int k = 2; k <= TOPK; k <<= 1)
        for (int j = k >> 1; j > 0; j >>= 1) {
            for (int idx = t; idx < TOPK; idx += 1024) {
                int ixj = idx ^ j;
                if (ixj > idx) {
                    unsigned long long a = s[idx], b = s[ixj];
                    bool desc = ((idx & k) == 0);
                    bool sw = desc ? (a < b) : (a > b);
                    if (sw) { s[idx] = b; s[ixj] = a; }
                }
            }
            __syncthreads();
        }
    for (int i = t; i < TOPK; i += 1024) keys[i] = s[i];
}

// ---------- 8: gather + max_coord ----------
__global__ __launch_bounds__(256) void k_gather(const unsigned long long* __restrict__ keys,
                                                const int* __restrict__ lab,
                                                const float4* __restrict__ box,
                                                int* __restrict__ cIdx,
                                                float* __restrict__ cScore,
                                                int* __restrict__ cLab,
                                                float4* __restrict__ cBox,
                                                unsigned* meta) {
    int k = blockIdx.x * 256 + threadIdx.x;
    unsigned long long key = keys[k];
    unsigned o = (unsigned)(key >> 32);
    unsigned a = ~(unsigned)(key & 0xFFFFFFFFu);
    float sc = ord2f(o);
    cIdx[k] = (int)a;
    cScore[k] = sc;
    cLab[k] = lab[a];
    float4 b = box[a];
    cBox[k] = b;
    if (sc > CONF) {
        if (b.x > 0.f) atomicMax(&meta[8], __float_as_uint(b.x));
        if (b.y > 0.f) atomicMax(&meta[8], __float_as_uint(b.y));
        if (b.z > 0.f) atomicMax(&meta[8], __float_as_uint(b.z));
        if (b.w > 0.f) atomicMax(&meta[8], __float_as_uint(b.w));
    }
}

// ---------- 9: offset boxes + areas ----------
__global__ __launch_bounds__(256) void k_offbox(const int* __restrict__ cLab,
                                                const float4* __restrict__ cBox,
                                                const unsigned* __restrict__ meta,
                                                float4* __restrict__ oBox,
                                                float* __restrict__ oArea) {
    int k = blockIdx.x * 256 + threadIdx.x;
    float mc = __uint_as_float(meta[8]) + 1.0f;
    float off = (float)cLab[k] * mc;
    float4 b = cBox[k];
    float4 ob;
    ob.x = b.x + off; ob.y = b.y + off; ob.z = b.z + off; ob.w = b.w + off;
    oBox[k] = ob;
    oArea[k] = fmaxf(ob.z - ob.x, 0.f) * fmaxf(ob.w - ob.y, 0.f);
}

// ---------- 10: suppression bitmask + diagonal sidecar ----------
// Diag[i] = M[i*64 + (i>>6)] : the intra-tile word of row i, stored compactly so
// k_nms's pass A needs only ONE coalesced 512B load per tile (prefetchable).
__global__ __launch_bounds__(256) void k_mask(const float4* __restrict__ oBox,
                                              const float* __restrict__ oArea,
                                              unsigned long long* __restrict__ M,
                                              unsigned long long* __restrict__ Diag) {
    int w = threadIdx.x;
    int i = blockIdx.x * 4 + threadIdx.y;
    float4 bi = oBox[i];
    float ai = oArea[i];
    unsigned long long bits = 0ull;
    int j0 = w << 6;
    for (int b = 0; b < 64; ++b) {
        int j = j0 + b;
        float4 bj = oBox[j];
        float aj = oArea[j];
        float ix1 = fmaxf(bi.x, bj.x), iy1 = fmaxf(bi.y, bj.y);
        float ix2 = fminf(bi.z, bj.z), iy2 = fminf(bi.w, bj.w);
        float inter = fmaxf(ix2 - ix1, 0.f) * fmaxf(iy2 - iy1, 0.f);
        float uni = ai + aj - inter;
        float iou = inter / fmaxf(uni, 1e-9f);
        if ((j > i) & (iou > IOUT)) bits |= (1ull << b);
    }
    M[(long)i * 64 + w] = bits;
    if (w == (i >> 6)) Diag[i] = bits;
}

// ---------- 11: greedy NMS, single wave, 64x64 tiled ----------
// SINGLE tile buffer R[64] (128 VGPR) with rotate-after-last-use: pass B reads
// R[b] once, then immediately reloads it with tile t+1's row b -> the t+1 loads
// have all of the remaining pass B plus tile t+1's pass A to land. Peak VGPR
// ~160 < 256 addressable (rounds 4-6 spilled: RA+RB=256 regs can never fit).
// Pass A uses the Diag sidecar: one register per tile, prefetched 2 deep.
__global__ __launch_bounds__(64, 1) void k_nms(const unsigned long long* __restrict__ M,
                                               const unsigned long long* __restrict__ Diag,
                                               const float* __restrict__ cScore,
                                               unsigned long long* __restrict__ keepW) {
    int lane = threadIdx.x;
    unsigned long long S = 0ull;
    // invalid-score bits: word b = ballot of lanes reading cScore[b*64+lane] (coalesced)
#pragma unroll 8
    for (int b = 0; b < 64; ++b) {
        float sc = cScore[(b << 6) + lane];
        unsigned long long bal = __ballot(!(sc > CONF));
        if (lane == b) S = bal;
    }
    const unsigned long long* Ml = M + lane;
    unsigned long long R[64];
#pragma unroll
    for (int b = 0; b < 64; ++b) R[b] = Ml[(long)b * 64];   // tile 0 rows
    unsigned long long d0 = Diag[lane];        // diag of tile 0
    unsigned long long d1 = Diag[64 + lane];   // diag of tile 1

#define NMS_TILE(t, RELOAD)                                                                         \
    {                                                                                               \
        unsigned long long dcur = d0;                                                               \
        d0 = d1;                                                                                    \
        if ((t) + 2 < 64) d1 = Diag[((t) + 2) * 64 + lane];                                         \
        unsigned long long s_tile =                                                                 \
            ((unsigned long long)(unsigned)__builtin_amdgcn_readlane((int)(unsigned)(S >> 32), (t)) \
             << 32) |                                                                               \
            (unsigned)__builtin_amdgcn_readlane((int)(unsigned)S, (t));                             \
        _Pragma("unroll")                                                                           \
        for (int b = 0; b < 64; ++b) {                                                              \
            unsigned rl = (unsigned)__builtin_amdgcn_readlane((int)(unsigned)dcur, b);              \
            unsigned rh = (unsigned)__builtin_amdgcn_readlane((int)(unsigned)(dcur >> 32), b);      \
            unsigned long long row = ((unsigned long long)rh << 32) | rl;                           \
            s_tile |= (((s_tile >> b) & 1ull) == 0ull) ? row : 0ull;  /* uniform chain */           \
        }                                                                                           \
        unsigned long long kt = ~s_tile;                                                            \
        const unsigned long long* Mnext = Ml + (long)((t) + 1) * 4096;                              \
        unsigned long long a0 = 0, a1 = 0, a2 = 0, a3 = 0, a4 = 0, a5 = 0, a6 = 0, a7 = 0;          \
        _Pragma("unroll")                                                                           \
        for (int b = 0; b < 64; b += 8) {                                                           \
            a0 |= R[b + 0] & (0ull - ((kt >> (b + 0)) & 1ull));                                     \
            if (RELOAD) R[b + 0] = Mnext[(long)(b + 0) * 64];                                       \
            a1 |= R[b + 1] & (0ull - ((kt >> (b + 1)) & 1ull));                                     \
            if (RELOAD) R[b + 1] = Mnext[(long)(b + 1) * 64];                                       \
            a2 |= R[b + 2] & (0ull - ((kt >> (b + 2)) & 1ull));                                     \
            if (RELOAD) R[b + 2] = Mnext[(long)(b + 2) * 64];                                       \
            a3 |= R[b + 3] & (0ull - ((kt >> (b + 3)) & 1ull));                                     \
            if (RELOAD) R[b + 3] = Mnext[(long)(b + 3) * 64];                                       \
            a4 |= R[b + 4] & (0ull - ((kt >> (b + 4)) & 1ull));                                     \
            if (RELOAD) R[b + 4] = Mnext[(long)(b + 4) * 64];                                       \
            a5 |= R[b + 5] & (0ull - ((kt >> (b + 5)) & 1ull));                                     \
            if (RELOAD) R[b + 5] = Mnext[(long)(b + 5) * 64];                                       \
            a6 |= R[b + 6] & (0ull - ((kt >> (b + 6)) & 1ull));                                     \
            if (RELOAD) R[b + 6] = Mnext[(long)(b + 6) * 64];                                       \
            a7 |= R[b + 7] & (0ull - ((kt >> (b + 7)) & 1ull));                                     \
            if (RELOAD) R[b + 7] = Mnext[(long)(b + 7) * 64];                                       \
        }                                                                                           \
        S |= ((a0 | a1) | (a2 | a3)) | ((a4 | a5) | (a6 | a7));                                     \
    }

    for (int t = 0; t < 63; ++t) NMS_TILE(t, true);
    NMS_TILE(63, false);
#undef NMS_TILE
    keepW[lane] = ~S;
}

// ---------- 12: finalize ----------
__global__ __launch_bounds__(256) void k_final(const unsigned long long* __restrict__ keepW,
                                               const float* __restrict__ cScore,
                                               const float4* __restrict__ cBox,
                                               const int* __restrict__ cIdx,
                                               const float* __restrict__ pred,
                                               const int* __restrict__ img,
                                               const int* __restrict__ inp,
                                               float* __restrict__ out,
                                               int out_size) {
    __shared__ int sel[MAXDET];
    __shared__ int nsel;
    int t = threadIdx.x;
    for (int i = t; i < out_size; i += 256) out[i] = 0.f;
    if (t == 0) nsel = 0;
    __syncthreads();
    if (t < 64) {
        unsigned long long kw = keepW[t];
        int cnt = __popcll(kw);
        int incl = cnt;
        for (int off = 1; off < 64; off <<= 1) {
            int v = __shfl_up(incl, off);
            if (t >= off) incl += v;
        }
        int rk = incl - cnt;
        if (t == 63) nsel = (incl < MAXDET) ? incl : MAXDET;
        unsigned long long m = kw;
        while (m) {
            int b = __ffsll((unsigned long long)m) - 1;
            m &= m - 1;
            if (rk < MAXDET) sel[rk] = (t << 6) + b;
            ++rk;
        }
    }
    __syncthreads();
    int nk = nsel;
    int ih_i = img[0], iw_i = img[1];
    int nh_i = inp[0], nw_i = inp[1];
    if (iw_i == 0) iw_i = img[2];
    if (nw_i == 0) nw_i = inp[2];
    float ih = (float)ih_i, iw = (float)iw_i;
    float nh = (float)nh_i, nw = (float)nw_i;
    float gain = fminf(nh / ih, nw / iw);
    float pad0 = (nh - ih * gain) * 0.5f;
    float pad1 = (nw - iw * gain) * 0.5f;
    for (int o = t; o < nk; o += 256) {
        int k = sel[o];
        float4 b = cBox[k];
        float x1 = fminf(fmaxf((b.x - pad1) / gain, 0.f), iw);
        float y1 = fminf(fmaxf((b.y - pad0) / gain, 0.f), ih);
        float x2 = fminf(fmaxf((b.z - pad1) / gain, 0.f), iw);
        float y2 = fminf(fmaxf((b.w - pad0) / gain, 0.f), ih);
        out[o * 4 + 0] = (x1 + x2) * 0.5f / iw;
        out[o * 4 + 1] = (y1 + y2) * 0.5f / ih;
        out[o * 4 + 2] = (x2 - x1) / iw;
        out[o * 4 + 3] = (y2 - y1) / ih;
        out[4 * MAXDET + o] = cScore[k];
    }
    for (int p = t; p < nk * N_CLS; p += 256) {
        int o = p / N_CLS, c = p - o * N_CLS;
        int a = cIdx[sel[o]];
        out[5 * MAXDET + p] = pred[(long)a * 85 + 5 + c];
    }
}

extern "C" void kernel_launch(void* const* d_in, const int* in_sizes, int n_in,
                              void* d_out, int out_size, void* d_ws, size_t ws_size,
                              hipStream_t stream) {
    const float* pred = (const float*)d_in[0];
    const int* img = (const int*)d_in[1];
    const int* inp = (const int*)d_in[2];
    float* out = (float*)d_out;
    unsigned char* W = (unsigned char*)d_ws;

    unsigned* hist                = (unsigned*)(W + 0);                // 262144 B
    unsigned* meta                = (unsigned*)(W + 262144);           // 256 B
    unsigned* ord                 = (unsigned*)(W + 262400);           // 480000 B
    int* lab                      = (int*)(W + 742400);                // 480000 B
    float4* box                   = (float4*)(W + 1222400);            // 1920000 B
    unsigned long long* keys      = (unsigned long long*)(W + 3142400);// 32768 B
    unsigned* eq                  = (unsigned*)(W + 3175168);          // 16384 B
    int* cIdx                     = (int*)(W + 3191552);               // 16384 B
    float* cScore                 = (float*)(W + 3207936);             // 16384 B
    int* cLab                     = (int*)(W + 3224320);               // 16384 B
    float4* cBox                  = (float4*)(W + 3240704);            // 65536 B
    float4* oBox                  = (float4*)(W + 3306240);            // 65536 B
    float* oArea                  = (float*)(W + 3371776);             // 16384 B
    unsigned long long* M         = (unsigned long long*)(W + 3388160);// 2097152 B
    unsigned long long* keepW     = (unsigned long long*)(W + 5485312);// 512 B
    // Diag (32768 B) aliases the ord region: ord is dead after k_compact,
    // Diag is written by k_mask (later) and read only by k_nms. 8B-aligned.
    unsigned long long* Diag      = (unsigned long long*)(W + 262400);

    int nb = (N_ANCH + 255) / 256;
    int ndb = (N_ANCH + DBLK - 1) / DBLK;
    k_zero<<<64, 1024, 0, stream>>>(hist, meta);
    k_decode<<<ndb, DBLK, 0, stream>>>(pred, ord, lab, box, hist);
    k_select<<<1, 1024, 0, stream>>>(hist, meta, 0);
    k_hist2<<<nb, 256, 0, stream>>>(ord, meta, hist);
    k_select<<<1, 1024, 0, stream>>>(hist, meta, 1);
    k_compact<<<nb, 256, 0, stream>>>(ord, meta, keys, eq);
    k_eqsort<<<1, 1024, 0, stream>>>(eq, meta, keys);
    k_sort<<<1, 1024, 0, stream>>>(keys);
    k_gather<<<16, 256, 0, stream>>>(keys, lab, box, cIdx, cScore, cLab, cBox, meta);
    k_offbox<<<16, 256, 0, stream>>>(cLab, cBox, meta, oBox, oArea);
    k_mask<<<1024, dim3(64, 4), 0, stream>>>(oBox, oArea, M, Diag);
    k_nms<<<1, 64, 0, stream>>>(M, Diag, cScore, keepW);
    k_final<<<1, 256, 0, stream>>>(keepW, cScore, cBox, cIdx, pred, img, inp, out, out_size);
}

// Round 8
// 273.654 us; speedup vs baseline: 1.6123x; 1.5570x over previous
//
#include <hip/hip_runtime.h>
#include <math.h>

#define N_ANCH 120000
#define N_CLS  80
#define TOPK   4096
#define MAXDET 100
#define CONF   0.25f
#define IOUT   0.4f
#define DBLK   128   // anchors per decode block

// ---------- helpers ----------
__device__ __forceinline__ unsigned f2ord(float f) {
    unsigned u = __float_as_uint(f);
    return (u & 0x80000000u) ? ~u : (u | 0x80000000u);
}
__device__ __forceinline__ float ord2f(unsigned o) {
    unsigned u = (o & 0x80000000u) ? (o & 0x7FFFFFFFu) : ~o;
    return __uint_as_float(u);
}
#define ORD_NEGINF 0x007FFFFFu   // f2ord(-INFINITY)

// ---------- 0: zero hist + meta ----------
__global__ __launch_bounds__(1024) void k_zero(unsigned* hist, unsigned* meta) {
    int i = blockIdx.x * 1024 + threadIdx.x;
    if (i < 65536) hist[i] = 0u;
    if (i < 64) meta[i] = 0u;
}

// ---------- 1: decode anchors (LDS-staged, coalesced) + histogram round 1 ----------
__global__ __launch_bounds__(DBLK) void k_decode(const float* __restrict__ pred,
                                                 unsigned* __restrict__ ord,
                                                 int* __restrict__ lab,
                                                 float4* __restrict__ box,
                                                 unsigned* __restrict__ hist) {
    __shared__ float s[DBLK * 85];   // 43520 B
    int blk = blockIdx.x;
    long basef = (long)blk * (DBLK * 85);
    long remf = (long)N_ANCH * 85 - basef;
    int nf = (int)(remf < (long)(DBLK * 85) ? remf : (long)(DBLK * 85));
    int tot4 = nf >> 2;  // all block float-counts are multiples of 4
    const float4* g4 = (const float4*)(pred + basef);
    float4* s4 = (float4*)s;
    for (int i = threadIdx.x; i < tot4; i += DBLK) s4[i] = g4[i];
    __syncthreads();
    int a = blk * DBLK + threadIdx.x;
    if (a >= N_ANCH) return;
    const float* p = s + threadIdx.x * 85;  // bank = (21*lane + c) % 32 -> 2-way, free
    float x = p[0], y = p[1], w = p[2], h = p[3], obj = p[4];
    float best = p[5];
    int bl = 0;
    for (int c = 1; c < N_CLS; ++c) {
        float v = p[5 + c];
        if (v > best) { best = v; bl = c; }   // first-max (argmax) semantics
    }
    float sc = obj * best;
    float hw = w * 0.5f, hh = h * 0.5f;
    float4 b;
    b.x = x - hw; b.y = y - hh; b.z = x + hw; b.w = y + hh;
    bool valid = sc > CONF;
    float m = valid ? sc : -INFINITY;
    unsigned o = f2ord(m);
    ord[a] = o;
    lab[a] = bl;
    box[a] = b;
    unsigned long long balInv = __ballot(!valid);
    if (valid) {
        atomicAdd(&hist[o >> 16], 1u);   // ~300 distinct exponent bins: distributed, cheap
    } else {
        int lane = threadIdx.x & 63;
        if (lane == __ffsll(balInv) - 1)
            atomicAdd(&hist[ORD_NEGINF >> 16], (unsigned)__popcll(balInv));
    }
}

// ---------- 2/4: histogram select (suffix scan over 65536 bins) ----------
__global__ __launch_bounds__(1024) void k_select(unsigned* hist, unsigned* meta, int mode) {
    __shared__ unsigned part[1024];
    int t = threadIdx.x;
    unsigned target = (mode == 0) ? (unsigned)TOPK : meta[2];
    int base = t * 64;
    unsigned local = 0;
    for (int i = 0; i < 64; ++i) local += hist[base + i];
    part[t] = local;
    __syncthreads();
    for (int off = 1; off < 1024; off <<= 1) {
        unsigned v = (t + off < 1024) ? part[t + off] : 0u;
        __syncthreads();
        part[t] += v;
        __syncthreads();
    }
    unsigned incl = part[t];
    unsigned after = (t + 1 < 1024) ? part[t + 1] : 0u;
    if (after < target && incl >= target) {
        unsigned c64[64];
#pragma unroll
        for (int i = 0; i < 64; ++i) c64[i] = hist[base + i];  // independent, pipelined
        unsigned run = after;
        for (int i = 63; i >= 0; --i) {
            unsigned c = c64[i];
            if (run + c >= target) {
                if (mode == 0) {
                    meta[0] = (unsigned)(base + i);
                    meta[1] = run;
                    meta[2] = (unsigned)TOPK - run;
                } else {
                    meta[3] = (meta[0] << 16) | (unsigned)(base + i);
                    meta[4] = meta[1] + run;
                    meta[5] = meta[2] - run;
                }
                break;
            }
            run += c;
        }
    }
    if (mode == 0) {
        for (int i = 0; i < 64; ++i) hist[base + i] = 0u;
    }
}

// ---------- 3: histogram round 2 (aggregate the constant -inf pattern defensively) ----------
__global__ __launch_bounds__(256) void k_hist2(const unsigned* __restrict__ ord,
                                               const unsigned* __restrict__ meta,
                                               unsigned* __restrict__ hist) {
    int a = blockIdx.x * 256 + threadIdx.x;
    if (a >= N_ANCH) return;
    unsigned o = ord[a];
    bool inBin = ((o >> 16) == meta[0]);
    bool isInv = inBin && (o == ORD_NEGINF);
    unsigned long long balInv = __ballot(isInv);
    if (inBin) {
        if (isInv) {
            int lane = threadIdx.x & 63;
            if (lane == __ffsll(balInv) - 1)
                atomicAdd(&hist[ORD_NEGINF & 0xFFFFu], (unsigned)__popcll(balInv));
        } else {
            atomicAdd(&hist[o & 0xFFFFu], 1u);
        }
    }
}

// ---------- 5: compact (warp-aggregated counter atomics; order within sets irrelevant) ----------
__global__ __launch_bounds__(256) void k_compact(const unsigned* __restrict__ ord,
                                                 unsigned* meta,
                                                 unsigned long long* __restrict__ keys,
                                                 unsigned* __restrict__ eq) {
    int a = blockIdx.x * 256 + threadIdx.x;
    if (a >= N_ANCH) return;
    unsigned o = ord[a];
    unsigned T = meta[3];
    int lane = threadIdx.x & 63;
    bool isGt = (o > T);
    bool isEq = (o == T);
    unsigned long long balGt = __ballot(isGt);
    unsigned long long balEq = __ballot(isEq);
    if (isGt) {
        int leader = __ffsll(balGt) - 1;
        unsigned base = 0;
        if (lane == leader) base = atomicAdd(&meta[6], (unsigned)__popcll(balGt));
        base = (unsigned)__shfl((int)base, leader);
        unsigned p = base + (unsigned)__popcll(balGt & ((1ull << lane) - 1ull));
        keys[p] = ((unsigned long long)o << 32) | (unsigned)(~(unsigned)a);
    } else if (isEq) {
        int leader = __ffsll(balEq) - 1;
        unsigned base = 0;
        if (lane == leader) base = atomicAdd(&meta[7], (unsigned)__popcll(balEq));
        base = (unsigned)__shfl((int)base, leader);
        unsigned p = base + (unsigned)__popcll(balEq & ((1ull << lane) - 1ull));
        if (p < TOPK) eq[p] = (unsigned)a;
    }
}

// ---------- 6: tie handling. Membership = remEq smallest tie indices. ----------
__global__ __launch_bounds__(1024) void k_eqsort(const unsigned* __restrict__ eq,
                                                 unsigned* meta,
                                                 unsigned long long* keys) {
    __shared__ unsigned s[TOPK];
    int t = threadIdx.x;
    unsigned n = meta[7]; if (n > TOPK) n = TOPK;
    unsigned remEq = meta[5];
    unsigned baseA = meta[4];
    unsigned T = meta[3];
    if (remEq == 0) return;
    if (n > remEq) {
        unsigned m = 1; while (m < n) m <<= 1;
        for (unsigned i = t; i < m; i += 1024) s[i] = (i < n) ? eq[i] : 0xFFFFFFFFu;
        __syncthreads();
        for (unsigned k = 2; k <= m; k <<= 1)
            for (unsigned j = k >> 1; j > 0; j >>= 1) {
                for (unsigned idx = t; idx < m; idx += 1024) {
                    unsigned ixj = idx ^ j;
                    if (ixj > idx) {
                        unsigned a = s[idx], b = s[ixj];
                        bool asc = ((idx & k) == 0);
                        bool sw = asc ? (a > b) : (a < b);
                        if (sw) { s[idx] = b; s[ixj] = a; }
                    }
                }
                __syncthreads();
            }
        for (unsigned r = t; r < remEq; r += 1024)
            keys[baseA + r] = ((unsigned long long)T << 32) | (unsigned)(~s[r]);
    } else {
        for (unsigned r = t; r < remEq; r += 1024)
            keys[baseA + r] = ((unsigned long long)T << 32) | (unsigned)(~eq[r]);
    }
}

// ---------- 7: bitonic sort 4096 keys descending ----------
__global__ __launch_bounds__(1024) void k_sort(unsigned long long* keys) {
    __shared__ unsigned long long s[TOPK];
    int t = threadIdx.x;
    for (int i = t; i < TOPK; i += 1024) s[i] = keys[i];
    __syncthreads();
    for (int k = 2; k <= TOPK; k <<= 1)
        for (int j = k >> 1; j > 0; j >>= 1) {
            for (int idx = t; idx < TOPK; idx += 1024) {
                int ixj = idx ^ j;
                if (ixj > idx) {
                    unsigned long long a = s[idx], b = s[ixj];
                    bool desc = ((idx & k) == 0);
                    bool sw = desc ? (a < b) : (a > b);
                    if (sw) { s[idx] = b; s[ixj] = a; }
                }
            }
            __syncthreads();
        }
    for (int i = t; i < TOPK; i += 1024) keys[i] = s[i];
}

// ---------- 8: gather + max_coord ----------
__global__ __launch_bounds__(256) void k_gather(const unsigned long long* __restrict__ keys,
                                                const int* __restrict__ lab,
                                                const float4* __restrict__ box,
                                                int* __restrict__ cIdx,
                                                float* __restrict__ cScore,
                                                int* __restrict__ cLab,
                                                float4* __restrict__ cBox,
                                                unsigned* meta) {
    int k = blockIdx.x * 256 + threadIdx.x;
    unsigned long long key = keys[k];
    unsigned o = (unsigned)(key >> 32);
    unsigned a = ~(unsigned)(key & 0xFFFFFFFFu);
    float sc = ord2f(o);
    cIdx[k] = (int)a;
    cScore[k] = sc;
    cLab[k] = lab[a];
    float4 b = box[a];
    cBox[k] = b;
    if (sc > CONF) {
        if (b.x > 0.f) atomicMax(&meta[8], __float_as_uint(b.x));
        if (b.y > 0.f) atomicMax(&meta[8], __float_as_uint(b.y));
        if (b.z > 0.f) atomicMax(&meta[8], __float_as_uint(b.z));
        if (b.w > 0.f) atomicMax(&meta[8], __float_as_uint(b.w));
    }
}

// ---------- 9: offset boxes + areas ----------
__global__ __launch_bounds__(256) void k_offbox(const int* __restrict__ cLab,
                                                const float4* __restrict__ cBox,
                                                const unsigned* __restrict__ meta,
                                                float4* __restrict__ oBox,
                                                float* __restrict__ oArea) {
    int k = blockIdx.x * 256 + threadIdx.x;
    float mc = __uint_as_float(meta[8]) + 1.0f;
    float off = (float)cLab[k] * mc;
    float4 b = cBox[k];
    float4 ob;
    ob.x = b.x + off; ob.y = b.y + off; ob.z = b.z + off; ob.w = b.w + off;
    oBox[k] = ob;
    oArea[k] = fmaxf(ob.z - ob.x, 0.f) * fmaxf(ob.w - ob.y, 0.f);
}

// ---------- 10: suppression bitmask + diagonal sidecar ----------
// Diag[i] = M[i*64 + (i>>6)] : the intra-tile word of row i, stored compactly so
// k_nms's pass A needs only ONE coalesced 512B load per tile (prefetchable).
__global__ __launch_bounds__(256) void k_mask(const float4* __restrict__ oBox,
                                              const float* __restrict__ oArea,
                                              unsigned long long* __restrict__ M,
                                              unsigned long long* __restrict__ Diag) {
    int w = threadIdx.x;
    int i = blockIdx.x * 4 + threadIdx.y;
    float4 bi = oBox[i];
    float ai = oArea[i];
    unsigned long long bits = 0ull;
    int j0 = w << 6;
    for (int b = 0; b < 64; ++b) {
        int j = j0 + b;
        float4 bj = oBox[j];
        float aj = oArea[j];
        float ix1 = fmaxf(bi.x, bj.x), iy1 = fmaxf(bi.y, bj.y);
        float ix2 = fminf(bi.z, bj.z), iy2 = fminf(bi.w, bj.w);
        float inter = fmaxf(ix2 - ix1, 0.f) * fmaxf(iy2 - iy1, 0.f);
        float uni = ai + aj - inter;
        float iou = inter / fmaxf(uni, 1e-9f);
        if ((j > i) & (iou > IOUT)) bits |= (1ull << b);
    }
    M[(long)i * 64 + w] = bits;
    if (w == (i >> 6)) Diag[i] = bits;
}

// ---------- 11: greedy NMS, single wave, 64x64 tiled, EARLY TERMINATION ----------
// Output only needs the top-MAXDET kept candidates; candidates are in rank
// (descending-score) order, so once the running kept-count reaches MAXDET no
// later row can enter the output (top_k ties resolve to lower index = earlier
// rank). Word w of keep is FINAL right after tile w's pass A. On early exit at
// tile T: keepW[w<T] = ~S, keepW[T] = kt (pass-A result), keepW[w>T] = 0.
// With sparse suppression (class-offset random boxes) this exits after ~2 of
// 64 tiles, making the per-tile latency cost (which resisted 3 rounds of
// register-pipelining attempts) mostly irrelevant.
__global__ __launch_bounds__(64, 1) void k_nms(const unsigned long long* __restrict__ M,
                                               const unsigned long long* __restrict__ Diag,
                                               const float* __restrict__ cScore,
                                               unsigned long long* __restrict__ keepW) {
    int lane = threadIdx.x;
    unsigned long long S = 0ull;
    // invalid-score bits: word b = ballot of lanes reading cScore[b*64+lane] (coalesced)
#pragma unroll 8
    for (int b = 0; b < 64; ++b) {
        float sc = cScore[(b << 6) + lane];
        unsigned long long bal = __ballot(!(sc > CONF));
        if (lane == b) S = bal;
    }
    unsigned long long d0 = Diag[lane];        // diag of tile 0
    unsigned long long d1 = Diag[64 + lane];   // diag of tile 1
    unsigned cnt = 0;
    int tstop = -1;                 // early-exit tile, -1 = ran all tiles
    unsigned long long ktStop = 0ull;

    for (int t = 0; t < 64; ++t) {
        unsigned long long dcur = d0;
        d0 = d1;
        if (t + 2 < 64) d1 = Diag[(t + 2) * 64 + lane];
        // ---- pass A: intra-tile greedy chain on uniform values (SALU) ----
        unsigned long long s_tile =
            ((unsigned long long)(unsigned)__builtin_amdgcn_readlane((int)(unsigned)(S >> 32), t)
             << 32) |
            (unsigned)__builtin_amdgcn_readlane((int)(unsigned)S, t);
#pragma unroll
        for (int b = 0; b < 64; ++b) {
            unsigned rl = (unsigned)__builtin_amdgcn_readlane((int)(unsigned)dcur, b);
            unsigned rh = (unsigned)__builtin_amdgcn_readlane((int)(unsigned)(dcur >> 32), b);
            unsigned long long row = ((unsigned long long)rh << 32) | rl;
            s_tile |= (((s_tile >> b) & 1ull) == 0ull) ? row : 0ull;
        }
        unsigned long long kt = ~s_tile;  // uniform keep mask for this tile's rows
        cnt += (unsigned)__popcll(kt);
        if (cnt >= MAXDET) { tstop = t; ktStop = kt; break; }  // skip pass B: only affects later words
        // ---- pass B: OR kept rows' masks into S (direct loads, 4 chains) ----
        const unsigned long long* Mrow = M + (long)(t << 6) * 64 + lane;
        unsigned long long a0 = 0, a1 = 0, a2 = 0, a3 = 0;
#pragma unroll
        for (int b = 0; b < 64; b += 4) {
            a0 |= Mrow[(long)(b + 0) * 64] & (0ull - ((kt >> (b + 0)) & 1ull));
            a1 |= Mrow[(long)(b + 1) * 64] & (0ull - ((kt >> (b + 1)) & 1ull));
            a2 |= Mrow[(long)(b + 2) * 64] & (0ull - ((kt >> (b + 2)) & 1ull));
            a3 |= Mrow[(long)(b + 3) * 64] & (0ull - ((kt >> (b + 3)) & 1ull));
        }
        S |= (a0 | a1) | (a2 | a3);
    }
    if (tstop >= 0) {
        keepW[lane] = (lane < tstop) ? ~S : (lane == tstop ? ktStop : 0ull);
    } else {
        keepW[lane] = ~S;
    }
}

// ---------- 12: finalize ----------
__global__ __launch_bounds__(256) void k_final(const unsigned long long* __restrict__ keepW,
                                               const float* __restrict__ cScore,
                                               const float4* __restrict__ cBox,
                                               const int* __restrict__ cIdx,
                                               const float* __restrict__ pred,
                                               const int* __restrict__ img,
                                               const int* __restrict__ inp,
                                               float* __restrict__ out,
                                               int out_size) {
    __shared__ int sel[MAXDET];
    __shared__ int nsel;
    int t = threadIdx.x;
    for (int i = t; i < out_size; i += 256) out[i] = 0.f;
    if (t == 0) nsel = 0;
    __syncthreads();
    if (t < 64) {
        unsigned long long kw = keepW[t];
        int cnt = __popcll(kw);
        int incl = cnt;
        for (int off = 1; off < 64; off <<= 1) {
            int v = __shfl_up(incl, off);
            if (t >= off) incl += v;
        }
        int rk = incl - cnt;
        if (t == 63) nsel = (incl < MAXDET) ? incl : MAXDET;
        unsigned long long m = kw;
        while (m) {
            int b = __ffsll((unsigned long long)m) - 1;
            m &= m - 1;
            if (rk < MAXDET) sel[rk] = (t << 6) + b;
            ++rk;
        }
    }
    __syncthreads();
    int nk = nsel;
    int ih_i = img[0], iw_i = img[1];
    int nh_i = inp[0], nw_i = inp[1];
    if (iw_i == 0) iw_i = img[2];
    if (nw_i == 0) nw_i = inp[2];
    float ih = (float)ih_i, iw = (float)iw_i;
    float nh = (float)nh_i, nw = (float)nw_i;
    float gain = fminf(nh / ih, nw / iw);
    float pad0 = (nh - ih * gain) * 0.5f;
    float pad1 = (nw - iw * gain) * 0.5f;
    for (int o = t; o < nk; o += 256) {
        int k = sel[o];
        float4 b = cBox[k];
        float x1 = fminf(fmaxf((b.x - pad1) / gain, 0.f), iw);
        float y1 = fminf(fmaxf((b.y - pad0) / gain, 0.f), ih);
        float x2 = fminf(fmaxf((b.z - pad1) / gain, 0.f), iw);
        float y2 = fminf(fmaxf((b.w - pad0) / gain, 0.f), ih);
        out[o * 4 + 0] = (x1 + x2) * 0.5f / iw;
        out[o * 4 + 1] = (y1 + y2) * 0.5f / ih;
        out[o * 4 + 2] = (x2 - x1) / iw;
        out[o * 4 + 3] = (y2 - y1) / ih;
        out[4 * MAXDET + o] = cScore[k];
    }
    for (int p = t; p < nk * N_CLS; p += 256) {
        int o = p / N_CLS, c = p - o * N_CLS;
        int a = cIdx[sel[o]];
        out[5 * MAXDET + p] = pred[(long)a * 85 + 5 + c];
    }
}

extern "C" void kernel_launch(void* const* d_in, const int* in_sizes, int n_in,
                              void* d_out, int out_size, void* d_ws, size_t ws_size,
                              hipStream_t stream) {
    const float* pred = (const float*)d_in[0];
    const int* img = (const int*)d_in[1];
    const int* inp = (const int*)d_in[2];
    float* out = (float*)d_out;
    unsigned char* W = (unsigned char*)d_ws;

    unsigned* hist                = (unsigned*)(W + 0);                // 262144 B
    unsigned* meta                = (unsigned*)(W + 262144);           // 256 B
    unsigned* ord                 = (unsigned*)(W + 262400);           // 480000 B
    int* lab                      = (int*)(W + 742400);                // 480000 B
    float4* box                   = (float4*)(W + 1222400);            // 1920000 B
    unsigned long long* keys      = (unsigned long long*)(W + 3142400);// 32768 B
    unsigned* eq                  = (unsigned*)(W + 3175168);          // 16384 B
    int* cIdx                     = (int*)(W + 3191552);               // 16384 B
    float* cScore                 = (float*)(W + 3207936);             // 16384 B
    int* cLab                     = (int*)(W + 3224320);               // 16384 B
    float4* cBox                  = (float4*)(W + 3240704);            // 65536 B
    float4* oBox                  = (float4*)(W + 3306240);            // 65536 B
    float* oArea                  = (float*)(W + 3371776);             // 16384 B
    unsigned long long* M         = (unsigned long long*)(W + 3388160);// 2097152 B
    unsigned long long* keepW     = (unsigned long long*)(W + 5485312);// 512 B
    // Diag (32768 B) aliases the ord region: ord is dead after k_compact,
    // Diag is written by k_mask (later) and read only by k_nms. 8B-aligned.
    unsigned long long* Diag      = (unsigned long long*)(W + 262400);

    int nb = (N_ANCH + 255) / 256;
    int ndb = (N_ANCH + DBLK - 1) / DBLK;
    k_zero<<<64, 1024, 0, stream>>>(hist, meta);
    k_decode<<<ndb, DBLK, 0, stream>>>(pred, ord, lab, box, hist);
    k_select<<<1, 1024, 0, stream>>>(hist, meta, 0);
    k_hist2<<<nb, 256, 0, stream>>>(ord, meta, hist);
    k_select<<<1, 1024, 0, stream>>>(hist, meta, 1);
    k_compact<<<nb, 256, 0, stream>>>(ord, meta, keys, eq);
    k_eqsort<<<1, 1024, 0, stream>>>(eq, meta, keys);
    k_sort<<<1, 1024, 0, stream>>>(keys);
    k_gather<<<16, 256, 0, stream>>>(keys, lab, box, cIdx, cScore, cLab, cBox, meta);
    k_offbox<<<16, 256, 0, stream>>>(cLab, cBox, meta, oBox, oArea);
    k_mask<<<1024, dim3(64, 4), 0, stream>>>(oBox, oArea, M, Diag);
    k_nms<<<1, 64, 0, stream>>>(M, Diag, cScore, keepW);
    k_final<<<1, 256, 0, stream>>>(keepW, cScore, cBox, cIdx, pred, img, inp, out, out_size);
}

// Round 9
// 231.545 us; speedup vs baseline: 1.9055x; 1.1819x over previous
//
#include <hip/hip_runtime.h>
#include <math.h>

#define N_ANCH 120000
#define N_CLS  80
#define TOPK   4096
#define MAXDET 100
#define CONF   0.25f
#define IOUT   0.4f
#define DBLK   128   // anchors per decode block

// ---------- helpers ----------
__device__ __forceinline__ unsigned f2ord(float f) {
    unsigned u = __float_as_uint(f);
    return (u & 0x80000000u) ? ~u : (u | 0x80000000u);
}
__device__ __forceinline__ float ord2f(unsigned o) {
    unsigned u = (o & 0x80000000u) ? (o & 0x7FFFFFFFu) : ~o;
    return __uint_as_float(u);
}
#define ORD_NEGINF 0x007FFFFFu   // f2ord(-INFINITY)
// Byte-swap bin remap (involution): consecutive logical bins -> 1KB apart.
// The ~256 hot bins (consecutive score exponents) hit ~256 distinct cache
// lines instead of ~12 -> atomic serialization (23cy/op, calibrated r3->r4)
// drops from ~70us to ~3us.
#define BMAP(b) ((((b) & 0xFFu) << 8) | ((unsigned)(b) >> 8))

// ---------- 0: zero hist + meta ----------
__global__ __launch_bounds__(1024) void k_zero(unsigned* hist, unsigned* meta) {
    int i = blockIdx.x * 1024 + threadIdx.x;
    if (i < 65536) hist[i] = 0u;
    if (i < 64) meta[i] = 0u;
}

// ---------- 1: decode anchors (LDS-staged, coalesced) + histogram round 1 (BMAP'd) ----------
__global__ __launch_bounds__(DBLK) void k_decode(const float* __restrict__ pred,
                                                 unsigned* __restrict__ ord,
                                                 int* __restrict__ lab,
                                                 float4* __restrict__ box,
                                                 unsigned* __restrict__ hist) {
    __shared__ float s[DBLK * 85];   // 43520 B
    int blk = blockIdx.x;
    long basef = (long)blk * (DBLK * 85);
    long remf = (long)N_ANCH * 85 - basef;
    int nf = (int)(remf < (long)(DBLK * 85) ? remf : (long)(DBLK * 85));
    int tot4 = nf >> 2;  // all block float-counts are multiples of 4
    const float4* g4 = (const float4*)(pred + basef);
    float4* s4 = (float4*)s;
    for (int i = threadIdx.x; i < tot4; i += DBLK) s4[i] = g4[i];
    __syncthreads();
    int a = blk * DBLK + threadIdx.x;
    if (a >= N_ANCH) return;
    const float* p = s + threadIdx.x * 85;  // bank = (21*lane + c) % 32 -> 2-way, free
    float x = p[0], y = p[1], w = p[2], h = p[3], obj = p[4];
    float best = p[5];
    int bl = 0;
    for (int c = 1; c < N_CLS; ++c) {
        float v = p[5 + c];
        if (v > best) { best = v; bl = c; }   // first-max (argmax) semantics
    }
    float sc = obj * best;
    float hw = w * 0.5f, hh = h * 0.5f;
    float4 b;
    b.x = x - hw; b.y = y - hh; b.z = x + hw; b.w = y + hh;
    bool valid = sc > CONF;
    float m = valid ? sc : -INFINITY;
    unsigned o = f2ord(m);
    ord[a] = o;
    lab[a] = bl;
    box[a] = b;
    unsigned long long balInv = __ballot(!valid);
    if (valid) {
        atomicAdd(&hist[BMAP(o >> 16)], 1u);
    } else {
        int lane = threadIdx.x & 63;
        if (lane == __ffsll(balInv) - 1)
            atomicAdd(&hist[BMAP(ORD_NEGINF >> 16)], (unsigned)__popcll(balInv));
    }
}

// ---------- 1b: un-permute round-1 histogram into a linear copy ----------
// 64 blocks spread the 65536 scattered reads across 64 CUs (~1us); the write
// is coalesced. k_select round 1 then reads linearly as before.
__global__ __launch_bounds__(1024) void k_unperm(const unsigned* __restrict__ hist,
                                                 unsigned* __restrict__ cnt) {
    int b = blockIdx.x * 1024 + threadIdx.x;
    cnt[b] = hist[BMAP(b)];
}

// ---------- 2/4: histogram select (suffix scan over 65536 bins) ----------
// mode 0 reads cnt (linear copy of BMAP'd round-1 hist) and re-zeros hist.
// mode 1 reads hist (round-2 bins, unmapped).
__global__ __launch_bounds__(1024) void k_select(unsigned* hist, const unsigned* __restrict__ cnt,
                                                 unsigned* meta, int mode) {
    __shared__ unsigned part[1024];
    int t = threadIdx.x;
    const unsigned* src = (mode == 0) ? cnt : hist;
    unsigned target = (mode == 0) ? (unsigned)TOPK : meta[2];
    int base = t * 64;
    unsigned local = 0;
    for (int i = 0; i < 64; ++i) local += src[base + i];
    part[t] = local;
    __syncthreads();
    for (int off = 1; off < 1024; off <<= 1) {
        unsigned v = (t + off < 1024) ? part[t + off] : 0u;
        __syncthreads();
        part[t] += v;
        __syncthreads();
    }
    unsigned incl = part[t];
    unsigned after = (t + 1 < 1024) ? part[t + 1] : 0u;
    if (after < target && incl >= target) {
        unsigned c64[64];
#pragma unroll
        for (int i = 0; i < 64; ++i) c64[i] = src[base + i];  // independent, pipelined
        unsigned run = after;
        for (int i = 63; i >= 0; --i) {
            unsigned c = c64[i];
            if (run + c >= target) {
                if (mode == 0) {
                    meta[0] = (unsigned)(base + i);
                    meta[1] = run;
                    meta[2] = (unsigned)TOPK - run;
                } else {
                    meta[3] = (meta[0] << 16) | (unsigned)(base + i);
                    meta[4] = meta[1] + run;
                    meta[5] = meta[2] - run;
                }
                break;
            }
            run += c;
        }
    }
    if (mode == 0) {
        for (int i = 0; i < 64; ++i) hist[base + i] = 0u;
    }
}

// ---------- 3: histogram round 2 (aggregate the constant -inf pattern defensively) ----------
__global__ __launch_bounds__(256) void k_hist2(const unsigned* __restrict__ ord,
                                               const unsigned* __restrict__ meta,
                                               unsigned* __restrict__ hist) {
    int a = blockIdx.x * 256 + threadIdx.x;
    if (a >= N_ANCH) return;
    unsigned o = ord[a];
    bool inBin = ((o >> 16) == meta[0]);
    bool isInv = inBin && (o == ORD_NEGINF);
    unsigned long long balInv = __ballot(isInv);
    if (inBin) {
        if (isInv) {
            int lane = threadIdx.x & 63;
            if (lane == __ffsll(balInv) - 1)
                atomicAdd(&hist[ORD_NEGINF & 0xFFFFu], (unsigned)__popcll(balInv));
        } else {
            atomicAdd(&hist[o & 0xFFFFu], 1u);
        }
    }
}

// ---------- 5: compact (block-aggregated counter atomics) ----------
// 469 block-level atomics instead of ~1875 wave-level ones (23cy/op on one
// line). Eq counter lives at meta[48] (different cache line from meta[6]).
__global__ __launch_bounds__(256) void k_compact(const unsigned* __restrict__ ord,
                                                 unsigned* meta,
                                                 unsigned long long* __restrict__ keys,
                                                 unsigned* __restrict__ eq) {
    __shared__ unsigned wcGt[4], wcEq[4], sBaseGt, sBaseEq;
    int a = blockIdx.x * 256 + threadIdx.x;
    int lane = threadIdx.x & 63, wv = threadIdx.x >> 6;
    unsigned T = meta[3];
    unsigned o = (a < N_ANCH) ? ord[a] : 0u;   // 0 is never > or == T (T>=CONF ord)
    bool isGt = (a < N_ANCH) && (o > T);
    bool isEq = (a < N_ANCH) && (o == T);
    unsigned long long balGt = __ballot(isGt);
    unsigned long long balEq = __ballot(isEq);
    if (lane == 0) {
        wcGt[wv] = (unsigned)__popcll(balGt);
        wcEq[wv] = (unsigned)__popcll(balEq);
    }
    __syncthreads();
    if (threadIdx.x == 0) {
        unsigned tg = wcGt[0] + wcGt[1] + wcGt[2] + wcGt[3];
        unsigned te = wcEq[0] + wcEq[1] + wcEq[2] + wcEq[3];
        sBaseGt = tg ? atomicAdd(&meta[6], tg) : 0u;
        sBaseEq = te ? atomicAdd(&meta[48], te) : 0u;
    }
    __syncthreads();
    unsigned long long ltmask = (lane == 63) ? ~0ull >> 1 : (1ull << lane) - 1ull;
    if (isGt) {
        unsigned p = sBaseGt;
        for (int w = 0; w < wv; ++w) p += wcGt[w];
        p += (unsigned)__popcll(balGt & ltmask);
        keys[p] = ((unsigned long long)o << 32) | (unsigned)(~(unsigned)a);
    } else if (isEq) {
        unsigned p = sBaseEq;
        for (int w = 0; w < wv; ++w) p += wcEq[w];
        p += (unsigned)__popcll(balEq & ltmask);
        if (p < TOPK) eq[p] = (unsigned)a;
    }
}

// ---------- 6: tie handling. Membership = remEq smallest tie indices. ----------
__global__ __launch_bounds__(1024) void k_eqsort(const unsigned* __restrict__ eq,
                                                 unsigned* meta,
                                                 unsigned long long* keys) {
    __shared__ unsigned s[TOPK];
    int t = threadIdx.x;
    unsigned n = meta[48]; if (n > TOPK) n = TOPK;
    unsigned remEq = meta[5];
    unsigned baseA = meta[4];
    unsigned T = meta[3];
    if (remEq == 0) return;
    if (n > remEq) {
        unsigned m = 1; while (m < n) m <<= 1;
        for (unsigned i = t; i < m; i += 1024) s[i] = (i < n) ? eq[i] : 0xFFFFFFFFu;
        __syncthreads();
        for (unsigned k = 2; k <= m; k <<= 1)
            for (unsigned j = k >> 1; j > 0; j >>= 1) {
                for (unsigned idx = t; idx < m; idx += 1024) {
                    unsigned ixj = idx ^ j;
                    if (ixj > idx) {
                        unsigned a = s[idx], b = s[ixj];
                        bool asc = ((idx & k) == 0);
                        bool sw = asc ? (a > b) : (a < b);
                        if (sw) { s[idx] = b; s[ixj] = a; }
                    }
                }
                __syncthreads();
            }
        for (unsigned r = t; r < remEq; r += 1024)
            keys[baseA + r] = ((unsigned long long)T << 32) | (unsigned)(~s[r]);
    } else {
        for (unsigned r = t; r < remEq; r += 1024)
            keys[baseA + r] = ((unsigned long long)T << 32) | (unsigned)(~eq[r]);
    }
}

// ---------- 7: bitonic sort 4096 keys descending ----------
__global__ __launch_bounds__(1024) void k_sort(unsigned long long* keys) {
    __shared__ unsigned long long s[TOPK];
    int t = threadIdx.x;
    for (int i = t; i < TOPK; i += 1024) s[i] = keys[i];
    __syncthreads();
    for (int k = 2; k <= TOPK; k <<= 1)
        for (int j = k >> 1; j > 0; j >>= 1) {
            for (int idx = t; idx < TOPK; idx += 1024) {
                int ixj = idx ^ j;
                if (ixj > idx) {
                    unsigned long long a = s[idx], b = s[ixj];
                    bool desc = ((idx & k) == 0);
                    bool sw = desc ? (a < b) : (a > b);
                    if (sw) { s[idx] = b; s[ixj] = a; }
                }
            }
            __syncthreads();
        }
    for (int i = t; i < TOPK; i += 1024) keys[i] = s[i];
}

// ---------- 8: gather + max_coord ----------
__global__ __launch_bounds__(256) void k_gather(const unsigned long long* __restrict__ keys,
                                                const int* __restrict__ lab,
                                                const float4* __restrict__ box,
                                                int* __restrict__ cIdx,
                                                float* __restrict__ cScore,
                                                int* __restrict__ cLab,
                                                float4* __restrict__ cBox,
                                                unsigned* meta) {
    int k = blockIdx.x * 256 + threadIdx.x;
    unsigned long long key = keys[k];
    unsigned o = (unsigned)(key >> 32);
    unsigned a = ~(unsigned)(key & 0xFFFFFFFFu);
    float sc = ord2f(o);
    cIdx[k] = (int)a;
    cScore[k] = sc;
    cLab[k] = lab[a];
    float4 b = box[a];
    cBox[k] = b;
    if (sc > CONF) {
        if (b.x > 0.f) atomicMax(&meta[8], __float_as_uint(b.x));
        if (b.y > 0.f) atomicMax(&meta[8], __float_as_uint(b.y));
        if (b.z > 0.f) atomicMax(&meta[8], __float_as_uint(b.z));
        if (b.w > 0.f) atomicMax(&meta[8], __float_as_uint(b.w));
    }
}

// ---------- 9: offset boxes + areas ----------
__global__ __launch_bounds__(256) void k_offbox(const int* __restrict__ cLab,
                                                const float4* __restrict__ cBox,
                                                const unsigned* __restrict__ meta,
                                                float4* __restrict__ oBox,
                                                float* __restrict__ oArea) {
    int k = blockIdx.x * 256 + threadIdx.x;
    float mc = __uint_as_float(meta[8]) + 1.0f;
    float off = (float)cLab[k] * mc;
    float4 b = cBox[k];
    float4 ob;
    ob.x = b.x + off; ob.y = b.y + off; ob.z = b.z + off; ob.w = b.w + off;
    oBox[k] = ob;
    oArea[k] = fmaxf(ob.z - ob.x, 0.f) * fmaxf(ob.w - ob.y, 0.f);
}

// ---------- 10: suppression bitmask + diagonal sidecar ----------
__global__ __launch_bounds__(256) void k_mask(const float4* __restrict__ oBox,
                                              const float* __restrict__ oArea,
                                              unsigned long long* __restrict__ M,
                                              unsigned long long* __restrict__ Diag) {
    int w = threadIdx.x;
    int i = blockIdx.x * 4 + threadIdx.y;
    float4 bi = oBox[i];
    float ai = oArea[i];
    unsigned long long bits = 0ull;
    int j0 = w << 6;
    for (int b = 0; b < 64; ++b) {
        int j = j0 + b;
        float4 bj = oBox[j];
        float aj = oArea[j];
        float ix1 = fmaxf(bi.x, bj.x), iy1 = fmaxf(bi.y, bj.y);
        float ix2 = fminf(bi.z, bj.z), iy2 = fminf(bi.w, bj.w);
        float inter = fmaxf(ix2 - ix1, 0.f) * fmaxf(iy2 - iy1, 0.f);
        float uni = ai + aj - inter;
        float iou = inter / fmaxf(uni, 1e-9f);
        if ((j > i) & (iou > IOUT)) bits |= (1ull << b);
    }
    M[(long)i * 64 + w] = bits;
    if (w == (i >> 6)) Diag[i] = bits;
}

// ---------- 11: greedy NMS, single wave, 64x64 tiled, EARLY TERMINATION ----------
__global__ __launch_bounds__(64, 1) void k_nms(const unsigned long long* __restrict__ M,
                                               const unsigned long long* __restrict__ Diag,
                                               const float* __restrict__ cScore,
                                               unsigned long long* __restrict__ keepW) {
    int lane = threadIdx.x;
    unsigned long long S = 0ull;
#pragma unroll 8
    for (int b = 0; b < 64; ++b) {
        float sc = cScore[(b << 6) + lane];
        unsigned long long bal = __ballot(!(sc > CONF));
        if (lane == b) S = bal;
    }
    unsigned long long d0 = Diag[lane];
    unsigned long long d1 = Diag[64 + lane];
    unsigned cnt = 0;
    int tstop = -1;
    unsigned long long ktStop = 0ull;

    for (int t = 0; t < 64; ++t) {
        unsigned long long dcur = d0;
        d0 = d1;
        if (t + 2 < 64) d1 = Diag[(t + 2) * 64 + lane];
        unsigned long long s_tile =
            ((unsigned long long)(unsigned)__builtin_amdgcn_readlane((int)(unsigned)(S >> 32), t)
             << 32) |
            (unsigned)__builtin_amdgcn_readlane((int)(unsigned)S, t);
#pragma unroll
        for (int b = 0; b < 64; ++b) {
            unsigned rl = (unsigned)__builtin_amdgcn_readlane((int)(unsigned)dcur, b);
            unsigned rh = (unsigned)__builtin_amdgcn_readlane((int)(unsigned)(dcur >> 32), b);
            unsigned long long row = ((unsigned long long)rh << 32) | rl;
            s_tile |= (((s_tile >> b) & 1ull) == 0ull) ? row : 0ull;
        }
        unsigned long long kt = ~s_tile;
        cnt += (unsigned)__popcll(kt);
        if (cnt >= MAXDET) { tstop = t; ktStop = kt; break; }
        const unsigned long long* Mrow = M + (long)(t << 6) * 64 + lane;
        unsigned long long a0 = 0, a1 = 0, a2 = 0, a3 = 0;
#pragma unroll
        for (int b = 0; b < 64; b += 4) {
            a0 |= Mrow[(long)(b + 0) * 64] & (0ull - ((kt >> (b + 0)) & 1ull));
            a1 |= Mrow[(long)(b + 1) * 64] & (0ull - ((kt >> (b + 1)) & 1ull));
            a2 |= Mrow[(long)(b + 2) * 64] & (0ull - ((kt >> (b + 2)) & 1ull));
            a3 |= Mrow[(long)(b + 3) * 64] & (0ull - ((kt >> (b + 3)) & 1ull));
        }
        S |= (a0 | a1) | (a2 | a3);
    }
    if (tstop >= 0) {
        keepW[lane] = (lane < tstop) ? ~S : (lane == tstop ? ktStop : 0ull);
    } else {
        keepW[lane] = ~S;
    }
}

// ---------- 12: finalize ----------
__global__ __launch_bounds__(256) void k_final(const unsigned long long* __restrict__ keepW,
                                               const float* __restrict__ cScore,
                                               const float4* __restrict__ cBox,
                                               const int* __restrict__ cIdx,
                                               const float* __restrict__ pred,
                                               const int* __restrict__ img,
                                               const int* __restrict__ inp,
                                               float* __restrict__ out,
                                               int out_size) {
    __shared__ int sel[MAXDET];
    __shared__ int nsel;
    int t = threadIdx.x;
    for (int i = t; i < out_size; i += 256) out[i] = 0.f;
    if (t == 0) nsel = 0;
    __syncthreads();
    if (t < 64) {
        unsigned long long kw = keepW[t];
        int cnt = __popcll(kw);
        int incl = cnt;
        for (int off = 1; off < 64; off <<= 1) {
            int v = __shfl_up(incl, off);
            if (t >= off) incl += v;
        }
        int rk = incl - cnt;
        if (t == 63) nsel = (incl < MAXDET) ? incl : MAXDET;
        unsigned long long m = kw;
        while (m) {
            int b = __ffsll((unsigned long long)m) - 1;
            m &= m - 1;
            if (rk < MAXDET) sel[rk] = (t << 6) + b;
            ++rk;
        }
    }
    __syncthreads();
    int nk = nsel;
    int ih_i = img[0], iw_i = img[1];
    int nh_i = inp[0], nw_i = inp[1];
    if (iw_i == 0) iw_i = img[2];
    if (nw_i == 0) nw_i = inp[2];
    float ih = (float)ih_i, iw = (float)iw_i;
    float nh = (float)nh_i, nw = (float)nw_i;
    float gain = fminf(nh / ih, nw / iw);
    float pad0 = (nh - ih * gain) * 0.5f;
    float pad1 = (nw - iw * gain) * 0.5f;
    for (int o = t; o < nk; o += 256) {
        int k = sel[o];
        float4 b = cBox[k];
        float x1 = fminf(fmaxf((b.x - pad1) / gain, 0.f), iw);
        float y1 = fminf(fmaxf((b.y - pad0) / gain, 0.f), ih);
        float x2 = fminf(fmaxf((b.z - pad1) / gain, 0.f), iw);
        float y2 = fminf(fmaxf((b.w - pad0) / gain, 0.f), ih);
        out[o * 4 + 0] = (x1 + x2) * 0.5f / iw;
        out[o * 4 + 1] = (y1 + y2) * 0.5f / ih;
        out[o * 4 + 2] = (x2 - x1) / iw;
        out[o * 4 + 3] = (y2 - y1) / ih;
        out[4 * MAXDET + o] = cScore[k];
    }
    for (int p = t; p < nk * N_CLS; p += 256) {
        int o = p / N_CLS, c = p - o * N_CLS;
        int a = cIdx[sel[o]];
        out[5 * MAXDET + p] = pred[(long)a * 85 + 5 + c];
    }
}

extern "C" void kernel_launch(void* const* d_in, const int* in_sizes, int n_in,
                              void* d_out, int out_size, void* d_ws, size_t ws_size,
                              hipStream_t stream) {
    const float* pred = (const float*)d_in[0];
    const int* img = (const int*)d_in[1];
    const int* inp = (const int*)d_in[2];
    float* out = (float*)d_out;
    unsigned char* W = (unsigned char*)d_ws;

    unsigned* hist                = (unsigned*)(W + 0);                // 262144 B
    unsigned* meta                = (unsigned*)(W + 262144);           // 256 B
    unsigned* ord                 = (unsigned*)(W + 262400);           // 480000 B
    int* lab                      = (int*)(W + 742400);                // 480000 B
    float4* box                   = (float4*)(W + 1222400);            // 1920000 B
    unsigned long long* keys      = (unsigned long long*)(W + 3142400);// 32768 B
    unsigned* eq                  = (unsigned*)(W + 3175168);          // 16384 B
    int* cIdx                     = (int*)(W + 3191552);               // 16384 B
    float* cScore                 = (float*)(W + 3207936);             // 16384 B
    int* cLab                     = (int*)(W + 3224320);               // 16384 B
    float4* cBox                  = (float4*)(W + 3240704);            // 65536 B
    float4* oBox                  = (float4*)(W + 3306240);            // 65536 B
    float* oArea                  = (float*)(W + 3371776);             // 16384 B
    unsigned long long* M         = (unsigned long long*)(W + 3388160);// 2097152 B
    unsigned long long* keepW     = (unsigned long long*)(W + 5485312);// 512 B
    // Diag (32768 B) aliases ord (dead after k_compact); written by k_mask.
    unsigned long long* Diag      = (unsigned long long*)(W + 262400);
    // cnt_lin (262144 B) aliases M (written by k_mask AFTER k_select is done).
    unsigned* cnt_lin             = (unsigned*)(W + 3388160);

    int nb = (N_ANCH + 255) / 256;
    int ndb = (N_ANCH + DBLK - 1) / DBLK;
    k_zero<<<64, 1024, 0, stream>>>(hist, meta);
    k_decode<<<ndb, DBLK, 0, stream>>>(pred, ord, lab, box, hist);
    k_unperm<<<64, 1024, 0, stream>>>(hist, cnt_lin);
    k_select<<<1, 1024, 0, stream>>>(hist, cnt_lin, meta, 0);
    k_hist2<<<nb, 256, 0, stream>>>(ord, meta, hist);
    k_select<<<1, 1024, 0, stream>>>(hist, cnt_lin, meta, 1);
    k_compact<<<nb, 256, 0, stream>>>(ord, meta, keys, eq);
    k_eqsort<<<1, 1024, 0, stream>>>(eq, meta, keys);
    k_sort<<<1, 1024, 0, stream>>>(keys);
    k_gather<<<16, 256, 0, stream>>>(keys, lab, box, cIdx, cScore, cLab, cBox, meta);
    k_offbox<<<16, 256, 0, stream>>>(cLab, cBox, meta, oBox, oArea);
    k_mask<<<1024, dim3(64, 4), 0, stream>>>(oBox, oArea, M, Diag);
    k_nms<<<1, 64, 0, stream>>>(M, Diag, cScore, keepW);
    k_final<<<1, 256, 0, stream>>>(keepW, cScore, cBox, cIdx, pred, img, inp, out, out_size);
}

// Round 10
// 207.111 us; speedup vs baseline: 2.1303x; 1.1180x over previous
//
#include <hip/hip_runtime.h>
#include <math.h>

#define N_ANCH 120000
#define N_CLS  80
#define TOPK   4096
#define MAXDET 100
#define CONF   0.25f
#define IOUT   0.4f
#define DBLK   128   // anchors per decode block

// ---------- helpers ----------
__device__ __forceinline__ unsigned f2ord(float f) {
    unsigned u = __float_as_uint(f);
    return (u & 0x80000000u) ? ~u : (u | 0x80000000u);
}
__device__ __forceinline__ float ord2f(unsigned o) {
    unsigned u = (o & 0x80000000u) ? (o & 0x7FFFFFFFu) : ~o;
    return __uint_as_float(u);
}
#define ORD_NEGINF 0x007FFFFFu   // f2ord(-INFINITY)
// Byte-swap bin remap (involution): consecutive logical bins -> 1KB apart.
#define BMAP(b) ((((b) & 0xFFu) << 8) | ((unsigned)(b) >> 8))

// ---------- 0: zero hist + meta ----------
__global__ __launch_bounds__(1024) void k_zero(unsigned* hist, unsigned* meta) {
    int i = blockIdx.x * 1024 + threadIdx.x;
    if (i < 65536) hist[i] = 0u;
    if (i < 64) meta[i] = 0u;
}

// ---------- 1: decode anchors (LDS-staged, coalesced) + histogram round 1 (BMAP'd) ----------
__global__ __launch_bounds__(DBLK) void k_decode(const float* __restrict__ pred,
                                                 unsigned* __restrict__ ord,
                                                 int* __restrict__ lab,
                                                 float4* __restrict__ box,
                                                 unsigned* __restrict__ hist) {
    __shared__ float s[DBLK * 85];   // 43520 B
    int blk = blockIdx.x;
    long basef = (long)blk * (DBLK * 85);
    long remf = (long)N_ANCH * 85 - basef;
    int nf = (int)(remf < (long)(DBLK * 85) ? remf : (long)(DBLK * 85));
    int tot4 = nf >> 2;  // all block float-counts are multiples of 4
    const float4* g4 = (const float4*)(pred + basef);
    float4* s4 = (float4*)s;
    for (int i = threadIdx.x; i < tot4; i += DBLK) s4[i] = g4[i];
    __syncthreads();
    int a = blk * DBLK + threadIdx.x;
    if (a >= N_ANCH) return;
    const float* p = s + threadIdx.x * 85;  // bank = (21*lane + c) % 32 -> 2-way, free
    float x = p[0], y = p[1], w = p[2], h = p[3], obj = p[4];
    float best = p[5];
    int bl = 0;
    for (int c = 1; c < N_CLS; ++c) {
        float v = p[5 + c];
        if (v > best) { best = v; bl = c; }   // first-max (argmax) semantics
    }
    float sc = obj * best;
    float hw = w * 0.5f, hh = h * 0.5f;
    float4 b;
    b.x = x - hw; b.y = y - hh; b.z = x + hw; b.w = y + hh;
    bool valid = sc > CONF;
    float m = valid ? sc : -INFINITY;
    unsigned o = f2ord(m);
    ord[a] = o;
    lab[a] = bl;
    box[a] = b;
    unsigned long long balInv = __ballot(!valid);
    if (valid) {
        atomicAdd(&hist[BMAP(o >> 16)], 1u);
    } else {
        int lane = threadIdx.x & 63;
        if (lane == __ffsll(balInv) - 1)
            atomicAdd(&hist[BMAP(ORD_NEGINF >> 16)], (unsigned)__popcll(balInv));
    }
}

// ---------- 1b: un-permute round-1 histogram into a linear copy ----------
__global__ __launch_bounds__(1024) void k_unperm(const unsigned* __restrict__ hist,
                                                 unsigned* __restrict__ cnt) {
    int b = blockIdx.x * 1024 + threadIdx.x;
    cnt[b] = hist[BMAP(b)];
}

// ---------- 2/4: histogram select (suffix scan over 65536 bins) ----------
__global__ __launch_bounds__(1024) void k_select(unsigned* hist, const unsigned* __restrict__ cnt,
                                                 unsigned* meta, int mode) {
    __shared__ unsigned part[1024];
    int t = threadIdx.x;
    const unsigned* src = (mode == 0) ? cnt : hist;
    unsigned target = (mode == 0) ? (unsigned)TOPK : meta[2];
    int base = t * 64;
    unsigned local = 0;
    for (int i = 0; i < 64; ++i) local += src[base + i];
    part[t] = local;
    __syncthreads();
    for (int off = 1; off < 1024; off <<= 1) {
        unsigned v = (t + off < 1024) ? part[t + off] : 0u;
        __syncthreads();
        part[t] += v;
        __syncthreads();
    }
    unsigned incl = part[t];
    unsigned after = (t + 1 < 1024) ? part[t + 1] : 0u;
    if (after < target && incl >= target) {
        unsigned c64[64];
#pragma unroll
        for (int i = 0; i < 64; ++i) c64[i] = src[base + i];  // independent, pipelined
        unsigned run = after;
        for (int i = 63; i >= 0; --i) {
            unsigned c = c64[i];
            if (run + c >= target) {
                if (mode == 0) {
                    meta[0] = (unsigned)(base + i);
                    meta[1] = run;
                    meta[2] = (unsigned)TOPK - run;
                } else {
                    meta[3] = (meta[0] << 16) | (unsigned)(base + i);
                    meta[4] = meta[1] + run;
                    meta[5] = meta[2] - run;
                }
                break;
            }
            run += c;
        }
    }
    if (mode == 0) {
        for (int i = 0; i < 64; ++i) hist[base + i] = 0u;
    }
}

// ---------- 3: histogram round 2 (aggregate the constant -inf pattern defensively) ----------
__global__ __launch_bounds__(256) void k_hist2(const unsigned* __restrict__ ord,
                                               const unsigned* __restrict__ meta,
                                               unsigned* __restrict__ hist) {
    int a = blockIdx.x * 256 + threadIdx.x;
    if (a >= N_ANCH) return;
    unsigned o = ord[a];
    bool inBin = ((o >> 16) == meta[0]);
    bool isInv = inBin && (o == ORD_NEGINF);
    unsigned long long balInv = __ballot(isInv);
    if (inBin) {
        if (isInv) {
            int lane = threadIdx.x & 63;
            if (lane == __ffsll(balInv) - 1)
                atomicAdd(&hist[ORD_NEGINF & 0xFFFFu], (unsigned)__popcll(balInv));
        } else {
            atomicAdd(&hist[o & 0xFFFFu], 1u);
        }
    }
}

// ---------- 5: compact (block-aggregated counter atomics) ----------
__global__ __launch_bounds__(256) void k_compact(const unsigned* __restrict__ ord,
                                                 unsigned* meta,
                                                 unsigned long long* __restrict__ keys,
                                                 unsigned* __restrict__ eq) {
    __shared__ unsigned wcGt[4], wcEq[4], sBaseGt, sBaseEq;
    int a = blockIdx.x * 256 + threadIdx.x;
    int lane = threadIdx.x & 63, wv = threadIdx.x >> 6;
    unsigned T = meta[3];
    unsigned o = (a < N_ANCH) ? ord[a] : 0u;   // 0 is never > or == T
    bool isGt = (a < N_ANCH) && (o > T);
    bool isEq = (a < N_ANCH) && (o == T);
    unsigned long long balGt = __ballot(isGt);
    unsigned long long balEq = __ballot(isEq);
    if (lane == 0) {
        wcGt[wv] = (unsigned)__popcll(balGt);
        wcEq[wv] = (unsigned)__popcll(balEq);
    }
    __syncthreads();
    if (threadIdx.x == 0) {
        unsigned tg = wcGt[0] + wcGt[1] + wcGt[2] + wcGt[3];
        unsigned te = wcEq[0] + wcEq[1] + wcEq[2] + wcEq[3];
        sBaseGt = tg ? atomicAdd(&meta[6], tg) : 0u;
        sBaseEq = te ? atomicAdd(&meta[48], te) : 0u;
    }
    __syncthreads();
    unsigned long long ltmask = (lane == 63) ? ~0ull >> 1 : (1ull << lane) - 1ull;
    if (isGt) {
        unsigned p = sBaseGt;
        for (int w = 0; w < wv; ++w) p += wcGt[w];
        p += (unsigned)__popcll(balGt & ltmask);
        keys[p] = ((unsigned long long)o << 32) | (unsigned)(~(unsigned)a);
    } else if (isEq) {
        unsigned p = sBaseEq;
        for (int w = 0; w < wv; ++w) p += wcEq[w];
        p += (unsigned)__popcll(balEq & ltmask);
        if (p < TOPK) eq[p] = (unsigned)a;
    }
}

// ---------- 6: tie handling. Membership = remEq smallest tie indices. ----------
__global__ __launch_bounds__(1024) void k_eqsort(const unsigned* __restrict__ eq,
                                                 unsigned* meta,
                                                 unsigned long long* keys) {
    __shared__ unsigned s[TOPK];
    int t = threadIdx.x;
    unsigned n = meta[48]; if (n > TOPK) n = TOPK;
    unsigned remEq = meta[5];
    unsigned baseA = meta[4];
    unsigned T = meta[3];
    if (remEq == 0) return;
    if (n > remEq) {
        unsigned m = 1; while (m < n) m <<= 1;
        for (unsigned i = t; i < m; i += 1024) s[i] = (i < n) ? eq[i] : 0xFFFFFFFFu;
        __syncthreads();
        for (unsigned k = 2; k <= m; k <<= 1)
            for (unsigned j = k >> 1; j > 0; j >>= 1) {
                for (unsigned idx = t; idx < m; idx += 1024) {
                    unsigned ixj = idx ^ j;
                    if (ixj > idx) {
                        unsigned a = s[idx], b = s[ixj];
                        bool asc = ((idx & k) == 0);
                        bool sw = asc ? (a > b) : (a < b);
                        if (sw) { s[idx] = b; s[ixj] = a; }
                    }
                }
                __syncthreads();
            }
        for (unsigned r = t; r < remEq; r += 1024)
            keys[baseA + r] = ((unsigned long long)T << 32) | (unsigned)(~s[r]);
    } else {
        for (unsigned r = t; r < remEq; r += 1024)
            keys[baseA + r] = ((unsigned long long)T << 32) | (unsigned)(~eq[r]);
    }
}

// ---------- 7: bitonic sort 4096 keys descending, 3-tier (reg / shfl / LDS) ----------
// Layout: idx = t*4 + r -> bits [1:0]=reg, [7:2]=lane, [11:8]=wave.
// j in {1,2}: in-register; j in {4..128}: shfl_xor(j>>2); j in {256..2048}: LDS.
// Only 10 of 78 steps touch LDS (vs all 78 before) -> ~8x less LDS traffic + barriers.
// takeMax = (low == desc) reproduces the classic network exactly.
__device__ __forceinline__ unsigned long long shflx64(unsigned long long v, int m) {
    unsigned lo = (unsigned)__shfl_xor((int)(unsigned)v, m, 64);
    unsigned hi = (unsigned)__shfl_xor((int)(unsigned)(v >> 32), m, 64);
    return ((unsigned long long)hi << 32) | lo;
}
__global__ __launch_bounds__(1024) void k_sort(unsigned long long* keys) {
    __shared__ unsigned long long lds[TOPK];  // 32 KB
    int t = threadIdx.x;
    int base = t << 2;
    unsigned long long key[4];
#pragma unroll
    for (int r = 0; r < 4; ++r) key[r] = keys[base + r];

    for (int k = 2; k <= TOPK; k <<= 1) {
        for (int j = k >> 1; j > 0; j >>= 1) {
            if (j >= 256) {
                __syncthreads();   // prior reads done before overwrite
#pragma unroll
                for (int r = 0; r < 4; ++r) lds[base + r] = key[r];
                __syncthreads();
#pragma unroll
                for (int r = 0; r < 4; ++r) {
                    int idx = base + r;
                    unsigned long long p = lds[idx ^ j];
                    bool takeMax = (((idx & j) == 0) == ((idx & k) == 0));
                    unsigned long long a = key[r];
                    key[r] = takeMax ? (a > p ? a : p) : (a > p ? p : a);
                }
            } else if (j >= 4) {
                int lm = j >> 2;
#pragma unroll
                for (int r = 0; r < 4; ++r) {
                    int idx = base + r;
                    unsigned long long p = shflx64(key[r], lm);
                    bool takeMax = (((idx & j) == 0) == ((idx & k) == 0));
                    unsigned long long a = key[r];
                    key[r] = takeMax ? (a > p ? a : p) : (a > p ? p : a);
                }
            } else {
#pragma unroll
                for (int r = 0; r < 4; ++r) {
                    int pr = r ^ j;
                    if (pr > r) {
                        int idx = base + r;
                        bool desc = (idx & k) == 0;
                        unsigned long long a = key[r], b = key[pr];
                        unsigned long long mx = a > b ? a : b, mn = a > b ? b : a;
                        key[r]  = desc ? mx : mn;
                        key[pr] = desc ? mn : mx;
                    }
                }
            }
        }
    }
#pragma unroll
    for (int r = 0; r < 4; ++r) keys[base + r] = key[r];
}

// ---------- 8: gather + max_coord ----------
__global__ __launch_bounds__(256) void k_gather(const unsigned long long* __restrict__ keys,
                                                const int* __restrict__ lab,
                                                const float4* __restrict__ box,
                                                int* __restrict__ cIdx,
                                                float* __restrict__ cScore,
                                                int* __restrict__ cLab,
                                                float4* __restrict__ cBox,
                                                unsigned* meta) {
    int k = blockIdx.x * 256 + threadIdx.x;
    unsigned long long key = keys[k];
    unsigned o = (unsigned)(key >> 32);
    unsigned a = ~(unsigned)(key & 0xFFFFFFFFu);
    float sc = ord2f(o);
    cIdx[k] = (int)a;
    cScore[k] = sc;
    cLab[k] = lab[a];
    float4 b = box[a];
    cBox[k] = b;
    if (sc > CONF) {
        if (b.x > 0.f) atomicMax(&meta[8], __float_as_uint(b.x));
        if (b.y > 0.f) atomicMax(&meta[8], __float_as_uint(b.y));
        if (b.z > 0.f) atomicMax(&meta[8], __float_as_uint(b.z));
        if (b.w > 0.f) atomicMax(&meta[8], __float_as_uint(b.w));
    }
}

// ---------- 9: offset boxes + areas ----------
__global__ __launch_bounds__(256) void k_offbox(const int* __restrict__ cLab,
                                                const float4* __restrict__ cBox,
                                                const unsigned* __restrict__ meta,
                                                float4* __restrict__ oBox,
                                                float* __restrict__ oArea) {
    int k = blockIdx.x * 256 + threadIdx.x;
    float mc = __uint_as_float(meta[8]) + 1.0f;
    float off = (float)cLab[k] * mc;
    float4 b = cBox[k];
    float4 ob;
    ob.x = b.x + off; ob.y = b.y + off; ob.z = b.z + off; ob.w = b.w + off;
    oBox[k] = ob;
    oArea[k] = fmaxf(ob.z - ob.x, 0.f) * fmaxf(ob.w - ob.y, 0.f);
}

// ---------- 10: suppression bitmask + diagonal sidecar ----------
__global__ __launch_bounds__(256) void k_mask(const float4* __restrict__ oBox,
                                              const float* __restrict__ oArea,
                                              unsigned long long* __restrict__ M,
                                              unsigned long long* __restrict__ Diag) {
    int w = threadIdx.x;
    int i = blockIdx.x * 4 + threadIdx.y;
    float4 bi = oBox[i];
    float ai = oArea[i];
    unsigned long long bits = 0ull;
    int j0 = w << 6;
    for (int b = 0; b < 64; ++b) {
        int j = j0 + b;
        float4 bj = oBox[j];
        float aj = oArea[j];
        float ix1 = fmaxf(bi.x, bj.x), iy1 = fmaxf(bi.y, bj.y);
        float ix2 = fminf(bi.z, bj.z), iy2 = fminf(bi.w, bj.w);
        float inter = fmaxf(ix2 - ix1, 0.f) * fmaxf(iy2 - iy1, 0.f);
        float uni = ai + aj - inter;
        float iou = inter / fmaxf(uni, 1e-9f);
        if ((j > i) & (iou > IOUT)) bits |= (1ull << b);
    }
    M[(long)i * 64 + w] = bits;
    if (w == (i >> 6)) Diag[i] = bits;
}

// ---------- 11: greedy NMS, single wave, 64x64 tiled, EARLY TERMINATION ----------
__global__ __launch_bounds__(64, 1) void k_nms(const unsigned long long* __restrict__ M,
                                               const unsigned long long* __restrict__ Diag,
                                               const float* __restrict__ cScore,
                                               unsigned long long* __restrict__ keepW) {
    int lane = threadIdx.x;
    unsigned long long S = 0ull;
#pragma unroll 8
    for (int b = 0; b < 64; ++b) {
        float sc = cScore[(b << 6) + lane];
        unsigned long long bal = __ballot(!(sc > CONF));
        if (lane == b) S = bal;
    }
    unsigned long long d0 = Diag[lane];
    unsigned long long d1 = Diag[64 + lane];
    unsigned cnt = 0;
    int tstop = -1;
    unsigned long long ktStop = 0ull;

    for (int t = 0; t < 64; ++t) {
        unsigned long long dcur = d0;
        d0 = d1;
        if (t + 2 < 64) d1 = Diag[(t + 2) * 64 + lane];
        unsigned long long s_tile =
            ((unsigned long long)(unsigned)__builtin_amdgcn_readlane((int)(unsigned)(S >> 32), t)
             << 32) |
            (unsigned)__builtin_amdgcn_readlane((int)(unsigned)S, t);
#pragma unroll
        for (int b = 0; b < 64; ++b) {
            unsigned rl = (unsigned)__builtin_amdgcn_readlane((int)(unsigned)dcur, b);
            unsigned rh = (unsigned)__builtin_amdgcn_readlane((int)(unsigned)(dcur >> 32), b);
            unsigned long long row = ((unsigned long long)rh << 32) | rl;
            s_tile |= (((s_tile >> b) & 1ull) == 0ull) ? row : 0ull;
        }
        unsigned long long kt = ~s_tile;
        cnt += (unsigned)__popcll(kt);
        if (cnt >= MAXDET) { tstop = t; ktStop = kt; break; }
        const unsigned long long* Mrow = M + (long)(t << 6) * 64 + lane;
        unsigned long long a0 = 0, a1 = 0, a2 = 0, a3 = 0;
#pragma unroll
        for (int b = 0; b < 64; b += 4) {
            a0 |= Mrow[(long)(b + 0) * 64] & (0ull - ((kt >> (b + 0)) & 1ull));
            a1 |= Mrow[(long)(b + 1) * 64] & (0ull - ((kt >> (b + 1)) & 1ull));
            a2 |= Mrow[(long)(b + 2) * 64] & (0ull - ((kt >> (b + 2)) & 1ull));
            a3 |= Mrow[(long)(b + 3) * 64] & (0ull - ((kt >> (b + 3)) & 1ull));
        }
        S |= (a0 | a1) | (a2 | a3);
    }
    if (tstop >= 0) {
        keepW[lane] = (lane < tstop) ? ~S : (lane == tstop ? ktStop : 0ull);
    } else {
        keepW[lane] = ~S;
    }
}

// ---------- 12: finalize ----------
__global__ __launch_bounds__(256) void k_final(const unsigned long long* __restrict__ keepW,
                                               const float* __restrict__ cScore,
                                               const float4* __restrict__ cBox,
                                               const int* __restrict__ cIdx,
                                               const float* __restrict__ pred,
                                               const int* __restrict__ img,
                                               const int* __restrict__ inp,
                                               float* __restrict__ out,
                                               int out_size) {
    __shared__ int sel[MAXDET];
    __shared__ int nsel;
    int t = threadIdx.x;
    for (int i = t; i < out_size; i += 256) out[i] = 0.f;
    if (t == 0) nsel = 0;
    __syncthreads();
    if (t < 64) {
        unsigned long long kw = keepW[t];
        int cnt = __popcll(kw);
        int incl = cnt;
        for (int off = 1; off < 64; off <<= 1) {
            int v = __shfl_up(incl, off);
            if (t >= off) incl += v;
        }
        int rk = incl - cnt;
        if (t == 63) nsel = (incl < MAXDET) ? incl : MAXDET;
        unsigned long long m = kw;
        while (m) {
            int b = __ffsll((unsigned long long)m) - 1;
            m &= m - 1;
            if (rk < MAXDET) sel[rk] = (t << 6) + b;
            ++rk;
        }
    }
    __syncthreads();
    int nk = nsel;
    int ih_i = img[0], iw_i = img[1];
    int nh_i = inp[0], nw_i = inp[1];
    if (iw_i == 0) iw_i = img[2];
    if (nw_i == 0) nw_i = inp[2];
    float ih = (float)ih_i, iw = (float)iw_i;
    float nh = (float)nh_i, nw = (float)nw_i;
    float gain = fminf(nh / ih, nw / iw);
    float pad0 = (nh - ih * gain) * 0.5f;
    float pad1 = (nw - iw * gain) * 0.5f;
    for (int o = t; o < nk; o += 256) {
        int k = sel[o];
        float4 b = cBox[k];
        float x1 = fminf(fmaxf((b.x - pad1) / gain, 0.f), iw);
        float y1 = fminf(fmaxf((b.y - pad0) / gain, 0.f), ih);
        float x2 = fminf(fmaxf((b.z - pad1) / gain, 0.f), iw);
        float y2 = fminf(fmaxf((b.w - pad0) / gain, 0.f), ih);
        out[o * 4 + 0] = (x1 + x2) * 0.5f / iw;
        out[o * 4 + 1] = (y1 + y2) * 0.5f / ih;
        out[o * 4 + 2] = (x2 - x1) / iw;
        out[o * 4 + 3] = (y2 - y1) / ih;
        out[4 * MAXDET + o] = cScore[k];
    }
    for (int p = t; p < nk * N_CLS; p += 256) {
        int o = p / N_CLS, c = p - o * N_CLS;
        int a = cIdx[sel[o]];
        out[5 * MAXDET + p] = pred[(long)a * 85 + 5 + c];
    }
}

extern "C" void kernel_launch(void* const* d_in, const int* in_sizes, int n_in,
                              void* d_out, int out_size, void* d_ws, size_t ws_size,
                              hipStream_t stream) {
    const float* pred = (const float*)d_in[0];
    const int* img = (const int*)d_in[1];
    const int* inp = (const int*)d_in[2];
    float* out = (float*)d_out;
    unsigned char* W = (unsigned char*)d_ws;

    unsigned* hist                = (unsigned*)(W + 0);                // 262144 B
    unsigned* meta                = (unsigned*)(W + 262144);           // 256 B
    unsigned* ord                 = (unsigned*)(W + 262400);           // 480000 B
    int* lab                      = (int*)(W + 742400);                // 480000 B
    float4* box                   = (float4*)(W + 1222400);            // 1920000 B
    unsigned long long* keys      = (unsigned long long*)(W + 3142400);// 32768 B
    unsigned* eq                  = (unsigned*)(W + 3175168);          // 16384 B
    int* cIdx                     = (int*)(W + 3191552);               // 16384 B
    float* cScore                 = (float*)(W + 3207936);             // 16384 B
    int* cLab                     = (int*)(W + 3224320);               // 16384 B
    float4* cBox                  = (float4*)(W + 3240704);            // 65536 B
    float4* oBox                  = (float4*)(W + 3306240);            // 65536 B
    float* oArea                  = (float*)(W + 3371776);             // 16384 B
    unsigned long long* M         = (unsigned long long*)(W + 3388160);// 2097152 B
    unsigned long long* keepW     = (unsigned long long*)(W + 5485312);// 512 B
    // Diag (32768 B) aliases ord (dead after k_compact); written by k_mask.
    unsigned long long* Diag      = (unsigned long long*)(W + 262400);
    // cnt_lin (262144 B) aliases M (written by k_mask AFTER k_select is done).
    unsigned* cnt_lin             = (unsigned*)(W + 3388160);

    int nb = (N_ANCH + 255) / 256;
    int ndb = (N_ANCH + DBLK - 1) / DBLK;
    k_zero<<<64, 1024, 0, stream>>>(hist, meta);
    k_decode<<<ndb, DBLK, 0, stream>>>(pred, ord, lab, box, hist);
    k_unperm<<<64, 1024, 0, stream>>>(hist, cnt_lin);
    k_select<<<1, 1024, 0, stream>>>(hist, cnt_lin, meta, 0);
    k_hist2<<<nb, 256, 0, stream>>>(ord, meta, hist);
    k_select<<<1, 1024, 0, stream>>>(hist, cnt_lin, meta, 1);
    k_compact<<<nb, 256, 0, stream>>>(ord, meta, keys, eq);
    k_eqsort<<<1, 1024, 0, stream>>>(eq, meta, keys);
    k_sort<<<1, 1024, 0, stream>>>(keys);
    k_gather<<<16, 256, 0, stream>>>(keys, lab, box, cIdx, cScore, cLab, cBox, meta);
    k_offbox<<<16, 256, 0, stream>>>(cLab, cBox, meta, oBox, oArea);
    k_mask<<<1024, dim3(64, 4), 0, stream>>>(oBox, oArea, M, Diag);
    k_nms<<<1, 64, 0, stream>>>(M, Diag, cScore, keepW);
    k_final<<<1, 256, 0, stream>>>(keepW, cScore, cBox, cIdx, pred, img, inp, out, out_size);
}

// Round 11
// 179.268 us; speedup vs baseline: 2.4611x; 1.1553x over previous
//
#include <hip/hip_runtime.h>
#include <math.h>

#define N_ANCH 120000
#define N_CLS  80
#define TOPK   4096
#define MAXDET 100
#define CONF   0.25f
#define IOUT   0.4f
#define DBLK   128   // anchors per decode block

// ---------- helpers ----------
__device__ __forceinline__ unsigned f2ord(float f) {
    unsigned u = __float_as_uint(f);
    return (u & 0x80000000u) ? ~u : (u | 0x80000000u);
}
__device__ __forceinline__ float ord2f(unsigned o) {
    unsigned u = (o & 0x80000000u) ? (o & 0x7FFFFFFFu) : ~o;
    return __uint_as_float(u);
}
#define ORD_NEGINF 0x007FFFFFu   // f2ord(-INFINITY)
// Byte-swap bin remap (involution): consecutive logical bins -> 1KB apart.
#define BMAP(b) ((((b) & 0xFFu) << 8) | ((unsigned)(b) >> 8))

// ---------- 0: zero hist + meta ----------
__global__ __launch_bounds__(1024) void k_zero(unsigned* hist, unsigned* meta) {
    int i = blockIdx.x * 1024 + threadIdx.x;
    if (i < 65536) hist[i] = 0u;
    if (i < 64) meta[i] = 0u;
}

// ---------- 1: decode anchors (LDS-staged, coalesced) + histogram round 1 (BMAP'd) ----------
__global__ __launch_bounds__(DBLK) void k_decode(const float* __restrict__ pred,
                                                 unsigned* __restrict__ ord,
                                                 int* __restrict__ lab,
                                                 float4* __restrict__ box,
                                                 unsigned* __restrict__ hist) {
    __shared__ float s[DBLK * 85];   // 43520 B
    int blk = blockIdx.x;
    long basef = (long)blk * (DBLK * 85);
    long remf = (long)N_ANCH * 85 - basef;
    int nf = (int)(remf < (long)(DBLK * 85) ? remf : (long)(DBLK * 85));
    int tot4 = nf >> 2;  // all block float-counts are multiples of 4
    const float4* g4 = (const float4*)(pred + basef);
    float4* s4 = (float4*)s;
    for (int i = threadIdx.x; i < tot4; i += DBLK) s4[i] = g4[i];
    __syncthreads();
    int a = blk * DBLK + threadIdx.x;
    if (a >= N_ANCH) return;
    const float* p = s + threadIdx.x * 85;  // bank = (21*lane + c) % 32 -> 2-way, free
    float x = p[0], y = p[1], w = p[2], h = p[3], obj = p[4];
    float best = p[5];
    int bl = 0;
    for (int c = 1; c < N_CLS; ++c) {
        float v = p[5 + c];
        if (v > best) { best = v; bl = c; }   // first-max (argmax) semantics
    }
    float sc = obj * best;
    float hw = w * 0.5f, hh = h * 0.5f;
    float4 b;
    b.x = x - hw; b.y = y - hh; b.z = x + hw; b.w = y + hh;
    bool valid = sc > CONF;
    float m = valid ? sc : -INFINITY;
    unsigned o = f2ord(m);
    ord[a] = o;
    lab[a] = bl;
    box[a] = b;
    unsigned long long balInv = __ballot(!valid);
    if (valid) {
        atomicAdd(&hist[BMAP(o >> 16)], 1u);
    } else {
        int lane = threadIdx.x & 63;
        if (lane == __ffsll(balInv) - 1)
            atomicAdd(&hist[BMAP(ORD_NEGINF >> 16)], (unsigned)__popcll(balInv));
    }
}

// ---------- 1b: un-permute round-1 histogram into a linear copy ----------
__global__ __launch_bounds__(1024) void k_unperm(const unsigned* __restrict__ hist,
                                                 unsigned* __restrict__ cnt) {
    int b = blockIdx.x * 1024 + threadIdx.x;
    cnt[b] = hist[BMAP(b)];
}

// ---------- 2/4: histogram select (suffix scan over 65536 bins) ----------
__global__ __launch_bounds__(1024) void k_select(unsigned* hist, const unsigned* __restrict__ cnt,
                                                 unsigned* meta, int mode) {
    __shared__ unsigned part[1024];
    int t = threadIdx.x;
    const unsigned* src = (mode == 0) ? cnt : hist;
    unsigned target = (mode == 0) ? (unsigned)TOPK : meta[2];
    int base = t * 64;
    unsigned local = 0;
    for (int i = 0; i < 64; ++i) local += src[base + i];
    part[t] = local;
    __syncthreads();
    for (int off = 1; off < 1024; off <<= 1) {
        unsigned v = (t + off < 1024) ? part[t + off] : 0u;
        __syncthreads();
        part[t] += v;
        __syncthreads();
    }
    unsigned incl = part[t];
    unsigned after = (t + 1 < 1024) ? part[t + 1] : 0u;
    if (after < target && incl >= target) {
        unsigned c64[64];
#pragma unroll
        for (int i = 0; i < 64; ++i) c64[i] = src[base + i];  // independent, pipelined
        unsigned run = after;
        for (int i = 63; i >= 0; --i) {
            unsigned c = c64[i];
            if (run + c >= target) {
                if (mode == 0) {
                    meta[0] = (unsigned)(base + i);
                    meta[1] = run;
                    meta[2] = (unsigned)TOPK - run;
                } else {
                    meta[3] = (meta[0] << 16) | (unsigned)(base + i);
                    meta[4] = meta[1] + run;
                    meta[5] = meta[2] - run;
                }
                break;
            }
            run += c;
        }
    }
    if (mode == 0) {
        for (int i = 0; i < 64; ++i) hist[base + i] = 0u;
    }
}

// ---------- 3: histogram round 2 (aggregate the constant -inf pattern defensively) ----------
__global__ __launch_bounds__(256) void k_hist2(const unsigned* __restrict__ ord,
                                               const unsigned* __restrict__ meta,
                                               unsigned* __restrict__ hist) {
    int a = blockIdx.x * 256 + threadIdx.x;
    if (a >= N_ANCH) return;
    unsigned o = ord[a];
    bool inBin = ((o >> 16) == meta[0]);
    bool isInv = inBin && (o == ORD_NEGINF);
    unsigned long long balInv = __ballot(isInv);
    if (inBin) {
        if (isInv) {
            int lane = threadIdx.x & 63;
            if (lane == __ffsll(balInv) - 1)
                atomicAdd(&hist[ORD_NEGINF & 0xFFFFu], (unsigned)__popcll(balInv));
        } else {
            atomicAdd(&hist[o & 0xFFFFu], 1u);
        }
    }
}

// ---------- 5: compact (block-aggregated counter atomics) ----------
__global__ __launch_bounds__(256) void k_compact(const unsigned* __restrict__ ord,
                                                 unsigned* meta,
                                                 unsigned long long* __restrict__ keys,
                                                 unsigned* __restrict__ eq) {
    __shared__ unsigned wcGt[4], wcEq[4], sBaseGt, sBaseEq;
    int a = blockIdx.x * 256 + threadIdx.x;
    int lane = threadIdx.x & 63, wv = threadIdx.x >> 6;
    unsigned T = meta[3];
    unsigned o = (a < N_ANCH) ? ord[a] : 0u;   // 0 is never > or == T
    bool isGt = (a < N_ANCH) && (o > T);
    bool isEq = (a < N_ANCH) && (o == T);
    unsigned long long balGt = __ballot(isGt);
    unsigned long long balEq = __ballot(isEq);
    if (lane == 0) {
        wcGt[wv] = (unsigned)__popcll(balGt);
        wcEq[wv] = (unsigned)__popcll(balEq);
    }
    __syncthreads();
    if (threadIdx.x == 0) {
        unsigned tg = wcGt[0] + wcGt[1] + wcGt[2] + wcGt[3];
        unsigned te = wcEq[0] + wcEq[1] + wcEq[2] + wcEq[3];
        sBaseGt = tg ? atomicAdd(&meta[6], tg) : 0u;
        sBaseEq = te ? atomicAdd(&meta[48], te) : 0u;
    }
    __syncthreads();
    unsigned long long ltmask = (lane == 63) ? ~0ull >> 1 : (1ull << lane) - 1ull;
    if (isGt) {
        unsigned p = sBaseGt;
        for (int w = 0; w < wv; ++w) p += wcGt[w];
        p += (unsigned)__popcll(balGt & ltmask);
        keys[p] = ((unsigned long long)o << 32) | (unsigned)(~(unsigned)a);
    } else if (isEq) {
        unsigned p = sBaseEq;
        for (int w = 0; w < wv; ++w) p += wcEq[w];
        p += (unsigned)__popcll(balEq & ltmask);
        if (p < TOPK) eq[p] = (unsigned)a;
    }
}

// ---------- 6: tie handling. Membership = remEq smallest tie indices. ----------
__global__ __launch_bounds__(1024) void k_eqsort(const unsigned* __restrict__ eq,
                                                 unsigned* meta,
                                                 unsigned long long* keys) {
    __shared__ unsigned s[TOPK];
    int t = threadIdx.x;
    unsigned n = meta[48]; if (n > TOPK) n = TOPK;
    unsigned remEq = meta[5];
    unsigned baseA = meta[4];
    unsigned T = meta[3];
    if (remEq == 0) return;
    if (n > remEq) {
        unsigned m = 1; while (m < n) m <<= 1;
        for (unsigned i = t; i < m; i += 1024) s[i] = (i < n) ? eq[i] : 0xFFFFFFFFu;
        __syncthreads();
        for (unsigned k = 2; k <= m; k <<= 1)
            for (unsigned j = k >> 1; j > 0; j >>= 1) {
                for (unsigned idx = t; idx < m; idx += 1024) {
                    unsigned ixj = idx ^ j;
                    if (ixj > idx) {
                        unsigned a = s[idx], b = s[ixj];
                        bool asc = ((idx & k) == 0);
                        bool sw = asc ? (a > b) : (a < b);
                        if (sw) { s[idx] = b; s[ixj] = a; }
                    }
                }
                __syncthreads();
            }
        for (unsigned r = t; r < remEq; r += 1024)
            keys[baseA + r] = ((unsigned long long)T << 32) | (unsigned)(~s[r]);
    } else {
        for (unsigned r = t; r < remEq; r += 1024)
            keys[baseA + r] = ((unsigned long long)T << 32) | (unsigned)(~eq[r]);
    }
}

// ---------- 7: bitonic sort 4096 keys descending, 3-tier (reg / shfl / LDS) ----------
__device__ __forceinline__ unsigned long long shflx64(unsigned long long v, int m) {
    unsigned lo = (unsigned)__shfl_xor((int)(unsigned)v, m, 64);
    unsigned hi = (unsigned)__shfl_xor((int)(unsigned)(v >> 32), m, 64);
    return ((unsigned long long)hi << 32) | lo;
}
__global__ __launch_bounds__(1024) void k_sort(unsigned long long* keys) {
    __shared__ unsigned long long lds[TOPK];  // 32 KB
    int t = threadIdx.x;
    int base = t << 2;
    unsigned long long key[4];
#pragma unroll
    for (int r = 0; r < 4; ++r) key[r] = keys[base + r];

    for (int k = 2; k <= TOPK; k <<= 1) {
        for (int j = k >> 1; j > 0; j >>= 1) {
            if (j >= 256) {
                __syncthreads();
#pragma unroll
                for (int r = 0; r < 4; ++r) lds[base + r] = key[r];
                __syncthreads();
#pragma unroll
                for (int r = 0; r < 4; ++r) {
                    int idx = base + r;
                    unsigned long long p = lds[idx ^ j];
                    bool takeMax = (((idx & j) == 0) == ((idx & k) == 0));
                    unsigned long long a = key[r];
                    key[r] = takeMax ? (a > p ? a : p) : (a > p ? p : a);
                }
            } else if (j >= 4) {
                int lm = j >> 2;
#pragma unroll
                for (int r = 0; r < 4; ++r) {
                    int idx = base + r;
                    unsigned long long p = shflx64(key[r], lm);
                    bool takeMax = (((idx & j) == 0) == ((idx & k) == 0));
                    unsigned long long a = key[r];
                    key[r] = takeMax ? (a > p ? a : p) : (a > p ? p : a);
                }
            } else {
#pragma unroll
                for (int r = 0; r < 4; ++r) {
                    int pr = r ^ j;
                    if (pr > r) {
                        int idx = base + r;
                        bool desc = (idx & k) == 0;
                        unsigned long long a = key[r], b = key[pr];
                        unsigned long long mx = a > b ? a : b, mn = a > b ? b : a;
                        key[r]  = desc ? mx : mn;
                        key[pr] = desc ? mn : mx;
                    }
                }
            }
        }
    }
#pragma unroll
    for (int r = 0; r < 4; ++r) keys[base + r] = key[r];
}

// ---------- 8: gather + max_coord ----------
__global__ __launch_bounds__(256) void k_gather(const unsigned long long* __restrict__ keys,
                                                const int* __restrict__ lab,
                                                const float4* __restrict__ box,
                                                int* __restrict__ cIdx,
                                                float* __restrict__ cScore,
                                                int* __restrict__ cLab,
                                                float4* __restrict__ cBox,
                                                unsigned* meta) {
    int k = blockIdx.x * 256 + threadIdx.x;
    unsigned long long key = keys[k];
    unsigned o = (unsigned)(key >> 32);
    unsigned a = ~(unsigned)(key & 0xFFFFFFFFu);
    float sc = ord2f(o);
    cIdx[k] = (int)a;
    cScore[k] = sc;
    cLab[k] = lab[a];
    float4 b = box[a];
    cBox[k] = b;
    if (sc > CONF) {
        if (b.x > 0.f) atomicMax(&meta[8], __float_as_uint(b.x));
        if (b.y > 0.f) atomicMax(&meta[8], __float_as_uint(b.y));
        if (b.z > 0.f) atomicMax(&meta[8], __float_as_uint(b.z));
        if (b.w > 0.f) atomicMax(&meta[8], __float_as_uint(b.w));
    }
}

// ---------- 9: offset boxes + areas ----------
__global__ __launch_bounds__(256) void k_offbox(const int* __restrict__ cLab,
                                                const float4* __restrict__ cBox,
                                                const unsigned* __restrict__ meta,
                                                float4* __restrict__ oBox,
                                                float* __restrict__ oArea) {
    int k = blockIdx.x * 256 + threadIdx.x;
    float mc = __uint_as_float(meta[8]) + 1.0f;
    float off = (float)cLab[k] * mc;
    float4 b = cBox[k];
    float4 ob;
    ob.x = b.x + off; ob.y = b.y + off; ob.z = b.z + off; ob.w = b.w + off;
    oBox[k] = ob;
    oArea[k] = fmaxf(ob.z - ob.x, 0.f) * fmaxf(ob.w - ob.y, 0.f);
}

// ---------- 10: suppression bitmask, ballot form ----------
// One wave per row i. For word jw, lane l computes the predicate for
// j = jw*64 + l: oBox/oArea loads are perfectly coalesced (consecutive lanes,
// consecutive addresses) vs the old stride-1024B gather (64 lines/instr).
// word = __ballot(bit) (bit l <-> j = jw*64+l, same layout as before).
// Words jw < i>>6 are all-zero (j>i impossible) -> skipped, halving IoU work.
// Lane jw latches its word; one coalesced 512B store per row writes all 64.
__global__ __launch_bounds__(256) void k_mask(const float4* __restrict__ oBox,
                                              const float* __restrict__ oArea,
                                              unsigned long long* __restrict__ M,
                                              unsigned long long* __restrict__ Diag) {
    int lane = threadIdx.x & 63;
    int i = blockIdx.x * 4 + (threadIdx.x >> 6);
    float4 bi = oBox[i];    // same address across lanes -> broadcast
    float ai = oArea[i];
    int w0 = i >> 6;
    unsigned long long myWord = 0ull;
    for (int jw = w0; jw < 64; ++jw) {
        int j = (jw << 6) + lane;
        float4 bj = oBox[j];            // coalesced
        float aj = oArea[j];            // coalesced
        float ix1 = fmaxf(bi.x, bj.x), iy1 = fmaxf(bi.y, bj.y);
        float ix2 = fminf(bi.z, bj.z), iy2 = fminf(bi.w, bj.w);
        float inter = fmaxf(ix2 - ix1, 0.f) * fmaxf(iy2 - iy1, 0.f);
        float uni = ai + aj - inter;
        float iou = inter / fmaxf(uni, 1e-9f);
        bool bit = (j > i) & (iou > IOUT);
        unsigned long long word = __ballot(bit);
        if (lane == jw) myWord = word;
    }
    M[(long)i * 64 + lane] = myWord;    // coalesced 512B/row (zeros for lane<w0)
    if (lane == w0) Diag[i] = myWord;
}

// ---------- 11: greedy NMS, single wave, 64x64 tiled, EARLY TERMINATION ----------
__global__ __launch_bounds__(64, 1) void k_nms(const unsigned long long* __restrict__ M,
                                               const unsigned long long* __restrict__ Diag,
                                               const float* __restrict__ cScore,
                                               unsigned long long* __restrict__ keepW) {
    int lane = threadIdx.x;
    unsigned long long S = 0ull;
#pragma unroll 8
    for (int b = 0; b < 64; ++b) {
        float sc = cScore[(b << 6) + lane];
        unsigned long long bal = __ballot(!(sc > CONF));
        if (lane == b) S = bal;
    }
    unsigned long long d0 = Diag[lane];
    unsigned long long d1 = Diag[64 + lane];
    unsigned cnt = 0;
    int tstop = -1;
    unsigned long long ktStop = 0ull;

    for (int t = 0; t < 64; ++t) {
        unsigned long long dcur = d0;
        d0 = d1;
        if (t + 2 < 64) d1 = Diag[(t + 2) * 64 + lane];
        unsigned long long s_tile =
            ((unsigned long long)(unsigned)__builtin_amdgcn_readlane((int)(unsigned)(S >> 32), t)
             << 32) |
            (unsigned)__builtin_amdgcn_readlane((int)(unsigned)S, t);
#pragma unroll
        for (int b = 0; b < 64; ++b) {
            unsigned rl = (unsigned)__builtin_amdgcn_readlane((int)(unsigned)dcur, b);
            unsigned rh = (unsigned)__builtin_amdgcn_readlane((int)(unsigned)(dcur >> 32), b);
            unsigned long long row = ((unsigned long long)rh << 32) | rl;
            s_tile |= (((s_tile >> b) & 1ull) == 0ull) ? row : 0ull;
        }
        unsigned long long kt = ~s_tile;
        cnt += (unsigned)__popcll(kt);
        if (cnt >= MAXDET) { tstop = t; ktStop = kt; break; }
        const unsigned long long* Mrow = M + (long)(t << 6) * 64 + lane;
        unsigned long long a0 = 0, a1 = 0, a2 = 0, a3 = 0;
#pragma unroll
        for (int b = 0; b < 64; b += 4) {
            a0 |= Mrow[(long)(b + 0) * 64] & (0ull - ((kt >> (b + 0)) & 1ull));
            a1 |= Mrow[(long)(b + 1) * 64] & (0ull - ((kt >> (b + 1)) & 1ull));
            a2 |= Mrow[(long)(b + 2) * 64] & (0ull - ((kt >> (b + 2)) & 1ull));
            a3 |= Mrow[(long)(b + 3) * 64] & (0ull - ((kt >> (b + 3)) & 1ull));
        }
        S |= (a0 | a1) | (a2 | a3);
    }
    if (tstop >= 0) {
        keepW[lane] = (lane < tstop) ? ~S : (lane == tstop ? ktStop : 0ull);
    } else {
        keepW[lane] = ~S;
    }
}

// ---------- 12: finalize ----------
__global__ __launch_bounds__(256) void k_final(const unsigned long long* __restrict__ keepW,
                                               const float* __restrict__ cScore,
                                               const float4* __restrict__ cBox,
                                               const int* __restrict__ cIdx,
                                               const float* __restrict__ pred,
                                               const int* __restrict__ img,
                                               const int* __restrict__ inp,
                                               float* __restrict__ out,
                                               int out_size) {
    __shared__ int sel[MAXDET];
    __shared__ int nsel;
    int t = threadIdx.x;
    for (int i = t; i < out_size; i += 256) out[i] = 0.f;
    if (t == 0) nsel = 0;
    __syncthreads();
    if (t < 64) {
        unsigned long long kw = keepW[t];
        int cnt = __popcll(kw);
        int incl = cnt;
        for (int off = 1; off < 64; off <<= 1) {
            int v = __shfl_up(incl, off);
            if (t >= off) incl += v;
        }
        int rk = incl - cnt;
        if (t == 63) nsel = (incl < MAXDET) ? incl : MAXDET;
        unsigned long long m = kw;
        while (m) {
            int b = __ffsll((unsigned long long)m) - 1;
            m &= m - 1;
            if (rk < MAXDET) sel[rk] = (t << 6) + b;
            ++rk;
        }
    }
    __syncthreads();
    int nk = nsel;
    int ih_i = img[0], iw_i = img[1];
    int nh_i = inp[0], nw_i = inp[1];
    if (iw_i == 0) iw_i = img[2];
    if (nw_i == 0) nw_i = inp[2];
    float ih = (float)ih_i, iw = (float)iw_i;
    float nh = (float)nh_i, nw = (float)nw_i;
    float gain = fminf(nh / ih, nw / iw);
    float pad0 = (nh - ih * gain) * 0.5f;
    float pad1 = (nw - iw * gain) * 0.5f;
    for (int o = t; o < nk; o += 256) {
        int k = sel[o];
        float4 b = cBox[k];
        float x1 = fminf(fmaxf((b.x - pad1) / gain, 0.f), iw);
        float y1 = fminf(fmaxf((b.y - pad0) / gain, 0.f), ih);
        float x2 = fminf(fmaxf((b.z - pad1) / gain, 0.f), iw);
        float y2 = fminf(fmaxf((b.w - pad0) / gain, 0.f), ih);
        out[o * 4 + 0] = (x1 + x2) * 0.5f / iw;
        out[o * 4 + 1] = (y1 + y2) * 0.5f / ih;
        out[o * 4 + 2] = (x2 - x1) / iw;
        out[o * 4 + 3] = (y2 - y1) / ih;
        out[4 * MAXDET + o] = cScore[k];
    }
    for (int p = t; p < nk * N_CLS; p += 256) {
        int o = p / N_CLS, c = p - o * N_CLS;
        int a = cIdx[sel[o]];
        out[5 * MAXDET + p] = pred[(long)a * 85 + 5 + c];
    }
}

extern "C" void kernel_launch(void* const* d_in, const int* in_sizes, int n_in,
                              void* d_out, int out_size, void* d_ws, size_t ws_size,
                              hipStream_t stream) {
    const float* pred = (const float*)d_in[0];
    const int* img = (const int*)d_in[1];
    const int* inp = (const int*)d_in[2];
    float* out = (float*)d_out;
    unsigned char* W = (unsigned char*)d_ws;

    unsigned* hist                = (unsigned*)(W + 0);                // 262144 B
    unsigned* meta                = (unsigned*)(W + 262144);           // 256 B
    unsigned* ord                 = (unsigned*)(W + 262400);           // 480000 B
    int* lab                      = (int*)(W + 742400);                // 480000 B
    float4* box                   = (float4*)(W + 1222400);            // 1920000 B
    unsigned long long* keys      = (unsigned long long*)(W + 3142400);// 32768 B
    unsigned* eq                  = (unsigned*)(W + 3175168);          // 16384 B
    int* cIdx                     = (int*)(W + 3191552);               // 16384 B
    float* cScore                 = (float*)(W + 3207936);             // 16384 B
    int* cLab                     = (int*)(W + 3224320);               // 16384 B
    float4* cBox                  = (float4*)(W + 3240704);            // 65536 B
    float4* oBox                  = (float4*)(W + 3306240);            // 65536 B
    float* oArea                  = (float*)(W + 3371776);             // 16384 B
    unsigned long long* M         = (unsigned long long*)(W + 3388160);// 2097152 B
    unsigned long long* keepW     = (unsigned long long*)(W + 5485312);// 512 B
    // Diag (32768 B) aliases ord (dead after k_compact); written by k_mask.
    unsigned long long* Diag      = (unsigned long long*)(W + 262400);
    // cnt_lin (262144 B) aliases M (written by k_mask AFTER k_select is done).
    unsigned* cnt_lin             = (unsigned*)(W + 3388160);

    int nb = (N_ANCH + 255) / 256;
    int ndb = (N_ANCH + DBLK - 1) / DBLK;
    k_zero<<<64, 1024, 0, stream>>>(hist, meta);
    k_decode<<<ndb, DBLK, 0, stream>>>(pred, ord, lab, box, hist);
    k_unperm<<<64, 1024, 0, stream>>>(hist, cnt_lin);
    k_select<<<1, 1024, 0, stream>>>(hist, cnt_lin, meta, 0);
    k_hist2<<<nb, 256, 0, stream>>>(ord, meta, hist);
    k_select<<<1, 1024, 0, stream>>>(hist, cnt_lin, meta, 1);
    k_compact<<<nb, 256, 0, stream>>>(ord, meta, keys, eq);
    k_eqsort<<<1, 1024, 0, stream>>>(eq, meta, keys);
    k_sort<<<1, 1024, 0, stream>>>(keys);
    k_gather<<<16, 256, 0, stream>>>(keys, lab, box, cIdx, cScore, cLab, cBox, meta);
    k_offbox<<<16, 256, 0, stream>>>(cLab, cBox, meta, oBox, oArea);
    k_mask<<<1024, 256, 0, stream>>>(oBox, oArea, M, Diag);
    k_nms<<<1, 64, 0, stream>>>(M, Diag, cScore, keepW);
    k_final<<<1, 256, 0, stream>>>(keepW, cScore, cBox, cIdx, pred, img, inp, out, out_size);
}